// Round 6
// baseline (71.489 us; speedup 1.0000x reference)
//
#include <hip/hip_runtime.h>
#include <math.h>

// NDF=512 NCF=256 NCC=256 EMB=16 FIELD=8 B=2048
// NH0=1024 CHANNEL=1017 HID=1020 K3=2041
// resb: [2048][2048] bf16 (cols 0..1023 = x, 1024..2040 = x_fm2, 2041..2047 = 0)

typedef __bf16 bf16x8 __attribute__((ext_vector_type(8)));
typedef float  f32x4  __attribute__((ext_vector_type(4)));

__device__ __forceinline__ unsigned short f2bf(float x) {
    union { float f; unsigned u; } c; c.f = x;
    unsigned r = c.u + 0x7fffu + ((c.u >> 16) & 1u);
    return (unsigned short)(r >> 16);
}
__device__ __forceinline__ float bf2f(unsigned short u) {
    union { unsigned u; float f; } c; c.u = ((unsigned)u) << 16;
    return c.f;
}

#define GLDS(g, l) __builtin_amdgcn_global_load_lds( \
    (const __attribute__((address_space(1))) void*)(g), \
    (__attribute__((address_space(3))) void*)(l), 16, 0, 0)

// ---------------------------------------------------------------------------
// MFMA GEMM: C = act(A(bf16,MxK) @ B^T(bf16,[N][K]) + bias)
// BM=128 BN=64, K-step 128, 512 threads (8 waves).
// Quads split K within the tile (quad q: k-cols [64q,64q+64)); wave tile 64x32.
// 2-buffer LDS (96 KB), one barrier + vmcnt(0) per 128-K step.
// 256B rows, XOR swizzle elem ^= (row&7)<<3 on BOTH sides.
// Cross-quad acc reduction via LDS at the end.
// Block->tile mapping is 2D-chunked per XCD (done by callers): each XCD owns
// a 4-row x 8-col sub-grid so its L2 working set is A 2MB + B 2MB.
// ---------------------------------------------------------------------------
template<int FUSE>   // FUSE 0: relu + bf16 store; FUSE 1: leaky + dot-W2 partials
__device__ __forceinline__ void mfma_gemm_body(
    const unsigned short* __restrict__ A, int lda,
    const unsigned short* __restrict__ B, int ldb,
    const float* __restrict__ bias,
    unsigned short* __restrict__ Cb, int ldc,                 // FUSE=0
    const float* __restrict__ W2p, float* __restrict__ part,  // FUSE=1
    int ccol0, int brow, int nbase, int K, int pcolb)
{
    __shared__ __align__(128) unsigned short As[2][128 * 128];  // 32KB x2
    __shared__ __align__(128) unsigned short Bs[2][64 * 128];   // 16KB x2

    const int t = threadIdx.x;
    const int w = t >> 6;
    const int l = t & 63;
    const int lr = l & 15, hi = l >> 4;
    const int lrx = (lr & 7) << 3;      // read-side swizzle XOR (elems)
    const int q   = w >> 2;             // k-half within the 128-K tile
    const int sub = w & 3;
    const int wr = sub >> 1, wc = sub & 1;
    const int kq = q << 6;              // quad k-elem base (0 or 64)

    f32x4 acc[4][2];
    #pragma unroll
    for (int m = 0; m < 4; ++m)
        #pragma unroll
        for (int n = 0; n < 2; ++n) acc[m][n] = f32x4{0.f, 0.f, 0.f, 0.f};

    const int nk = K >> 7;              // 128-K steps

    auto STAGE = [&](int buf, int k0) {
        #pragma unroll
        for (int i = 0; i < 4; ++i) {   // A: wave stages 16 rows (4 x 4-row instrs)
            const int r0 = w * 16 + i * 4;
            const int row = r0 + (l >> 4);
            const int se = ((l & 15) ^ (row & 7)) << 3;
            GLDS(A + (size_t)(brow + row) * lda + k0 + se, &As[buf][r0 * 128]);
        }
        #pragma unroll
        for (int i = 0; i < 2; ++i) {   // B: wave stages 8 rows
            const int r0 = w * 8 + i * 4;
            const int row = r0 + (l >> 4);
            const int se = ((l & 15) ^ (row & 7)) << 3;
            GLDS(B + (size_t)(nbase + row) * ldb + k0 + se, &Bs[buf][r0 * 128]);
        }
    };

    STAGE(0, 0);

    for (int tt = 0; tt < nk; ++tt) {
        asm volatile("s_waitcnt vmcnt(0)" ::: "memory");
        __builtin_amdgcn_s_barrier();
        if (tt + 1 < nk) STAGE((tt + 1) & 1, (tt + 1) << 7);

        const unsigned short* pa = &As[tt & 1][0];
        const unsigned short* pb = &Bs[tt & 1][0];
        bf16x8 af[4][2], bfv[2][2];
        #pragma unroll
        for (int m = 0; m < 4; ++m) {
            const int row = wr * 64 + m * 16 + lr;
            #pragma unroll
            for (int ks = 0; ks < 2; ++ks)
                af[m][ks] = *(const bf16x8*)&pa[row * 128 + ((kq + ks * 32 + hi * 8) ^ lrx)];
        }
        #pragma unroll
        for (int n = 0; n < 2; ++n) {
            const int row = wc * 32 + n * 16 + lr;
            #pragma unroll
            for (int ks = 0; ks < 2; ++ks)
                bfv[n][ks] = *(const bf16x8*)&pb[row * 128 + ((kq + ks * 32 + hi * 8) ^ lrx)];
        }
        #pragma unroll
        for (int ks = 0; ks < 2; ++ks)
            #pragma unroll
            for (int m = 0; m < 4; ++m)
                #pragma unroll
                for (int n = 0; n < 2; ++n)
                    acc[m][n] = __builtin_amdgcn_mfma_f32_16x16x32_bf16(af[m][ks], bfv[n][ks], acc[m][n], 0, 0, 0);
    }

    // Cross-quad reduction: quad1 writes accs to LDS (aliasing As), quad0 adds.
    __syncthreads();
    float* red = (float*)&As[0][0];     // 32 KB needed, 64 KB available
    if (q == 1) {
        #pragma unroll
        for (int m = 0; m < 4; ++m)
            #pragma unroll
            for (int n = 0; n < 2; ++n)
                *(f32x4*)&red[(((sub * 8) + m * 2 + n) * 64 + l) * 4] = acc[m][n];
    }
    __syncthreads();
    if (q != 0) return;

    #pragma unroll
    for (int m = 0; m < 4; ++m)
        #pragma unroll
        for (int n = 0; n < 2; ++n)
            acc[m][n] += *(const f32x4*)&red[(((sub * 8) + m * 2 + n) * 64 + l) * 4];

    // Epilogue. C/D map: col = lane&15, row = (lane>>4)*4 + j.
    const int orow0 = brow + wr * 64 + hi * 4;
    if (FUSE) {
        float bz[2], w2v[2];
        #pragma unroll
        for (int n = 0; n < 2; ++n) {
            const int col = ccol0 + wc * 32 + n * 16 + lr;
            bz[n] = bias[col];
            w2v[n] = W2p[col];
        }
        #pragma unroll
        for (int m = 0; m < 4; ++m) {
            #pragma unroll
            for (int j = 0; j < 4; ++j) {
                float p = 0.f;
                #pragma unroll
                for (int n = 0; n < 2; ++n) {
                    float z = acc[m][n][j] + bz[n];
                    z = (z > 0.f) ? z : 0.01f * z;
                    p = fmaf(z, w2v[n], p);
                }
                p += __shfl_xor(p, 1, 64);
                p += __shfl_xor(p, 2, 64);
                p += __shfl_xor(p, 4, 64);
                p += __shfl_xor(p, 8, 64);
                if (lr == 0)
                    part[(size_t)(pcolb + wc) * 2048 + orow0 + m * 16 + j] = p;
            }
        }
    } else {
        #pragma unroll
        for (int m = 0; m < 4; ++m) {
            #pragma unroll
            for (int n = 0; n < 2; ++n) {
                const int col = ccol0 + wc * 32 + n * 16 + lr;
                const float bz = bias[col];
                #pragma unroll
                for (int j = 0; j < 4; ++j) {
                    float z = acc[m][n][j] + bz;
                    z = fmaxf(z, 0.f);
                    Cb[(size_t)(orow0 + m * 16 + j) * ldc + col] = f2bf(z);
                }
            }
        }
    }
}

// 2D-chunked XCD mapping: xcd = bid&7 owns rows [4*(xcd>>1)..+4) x cols
// [8*(xcd&1)..+8) of the 16x16 tile grid -> per-XCD L2 working set ~4MB.
__device__ __forceinline__ void chunk_map(int bid, int& rowb, int& cb) {
    const int xcd = bid & 7, idx = bid >> 3;
    rowb = (xcd >> 1) * 4 + (idx >> 3);
    cb   = (xcd & 1) * 8 + (idx & 7);
}

__global__ __launch_bounds__(512) void gemm_top_mfma(
    const unsigned short* __restrict__ dxb, const unsigned short* __restrict__ cxb,
    const unsigned short* __restrict__ WdT, const unsigned short* __restrict__ WcT,
    const float* __restrict__ bd, const float* __restrict__ bc,
    unsigned short* __restrict__ resb)
{
    int rowb, cb;
    chunk_map(blockIdx.x, rowb, cb);
    const int brow = rowb * 128;
    const int ccol0 = cb * 64;
    if (cb < 8)
        mfma_gemm_body<0>(dxb, 512, WdT, 512, bd, resb, 2048,
                          nullptr, nullptr, ccol0, brow, ccol0, 512, 0);
    else
        mfma_gemm_body<0>(cxb, 256, WcT, 256, bc - 512, resb, 2048,
                          nullptr, nullptr, ccol0, brow, ccol0 - 512, 256, 0);
}

__global__ __launch_bounds__(512) void gemm_w1_mfma(
    const unsigned short* __restrict__ resb, const unsigned short* __restrict__ W1T,
    const float* __restrict__ b1p, const float* __restrict__ W2p,
    float* __restrict__ part)
{
    int rowb, cb;
    chunk_map(blockIdx.x, rowb, cb);
    mfma_gemm_body<1>(resb, 2048, W1T, 2048, b1p, nullptr, 0,
                      W2p, part, cb * 64, rowb * 128, cb * 64, 2048, cb * 2);
}

// ---------------------------------------------------------------------------
// prep_all: blocks 0..607 = transposes (Wd, Wc, W1 -> bf16 n-major);
//           blocks 608..  = elementwise prep (bf16 casts, pads, Ve).
// ---------------------------------------------------------------------------
#define N_DX (2048*512)
#define N_CX (2048*256)
#define N_V  (1017*128)
#define PREP_TOTAL (N_DX + N_CX + N_V + 1024 + 1024 + 8136)

__global__ __launch_bounds__(256) void prep_all(
    const float* __restrict__ dx, const float* __restrict__ cx,
    const float* __restrict__ v,  const float* __restrict__ b1,
    const float* __restrict__ W2,
    const float* __restrict__ Wd, const float* __restrict__ Wc, const float* __restrict__ W1,
    unsigned short* __restrict__ dxb, unsigned short* __restrict__ cxb,
    unsigned short* __restrict__ vb, float* __restrict__ b1p,
    float* __restrict__ W2p, float* __restrict__ Ve,
    unsigned short* __restrict__ WdT, unsigned short* __restrict__ WcT,
    unsigned short* __restrict__ W1T)
{
    __shared__ float tile[64][65];
    if (blockIdx.x < 608) {
        int bid = blockIdx.x;
        const float* in; unsigned short* out;
        int K0, N0, ldin, Kout, kt, nt;
        if (bid < 64) {
            in = Wd; out = WdT; K0 = 512; N0 = 512; ldin = 512; Kout = 512;
            kt = bid & 7; nt = bid >> 3;
        } else if (bid < 96) {
            bid -= 64;
            in = Wc; out = WcT; K0 = 256; N0 = 512; ldin = 512; Kout = 256;
            kt = bid & 3; nt = bid >> 2;
        } else {
            bid -= 96;
            in = W1; out = W1T; K0 = 2041; N0 = 1020; ldin = 1020; Kout = 2048;
            kt = bid & 31; nt = bid >> 5;
        }
        const int k0 = kt * 64, n0 = nt * 64;
        const int tt = threadIdx.x;
        const int nl = tt & 63, kq = tt >> 6;
        #pragma unroll
        for (int i = 0; i < 16; ++i) {
            const int kl = kq + i * 4;
            const int gk = k0 + kl, gn = n0 + nl;
            tile[kl][nl] = (gk < K0 && gn < N0) ? in[(size_t)gk * ldin + gn] : 0.f;
        }
        __syncthreads();
        const int kl2 = tt & 63, nq = tt >> 6;
        #pragma unroll
        for (int i = 0; i < 16; ++i) {
            const int nl2 = nq + i * 4;
            out[(size_t)(n0 + nl2) * Kout + k0 + kl2] = f2bf(tile[kl2][nl2]);
        }
        return;
    }
    int j = (blockIdx.x - 608) * 256 + threadIdx.x;
    if (j < N_DX) { dxb[j] = f2bf(dx[j]); return; }
    j -= N_DX;
    if (j < N_CX) { cxb[j] = f2bf(cx[j]); return; }
    j -= N_CX;
    if (j < N_V)  { vb[j] = f2bf(v[j]); return; }
    j -= N_V;
    if (j < 1024) { b1p[j] = (j < 1020) ? b1[j] : 0.f; return; }
    j -= 1024;
    if (j < 1024) { W2p[j] = (j < 1020) ? W2[j] : 0.f; return; }
    j -= 1024;
    if (j >= 8136) return;
    float s = 0.f;
    const float* vp = v + (size_t)j * 16;
    #pragma unroll
    for (int e = 0; e < 16; ++e) { float vv = bf2f(f2bf(vp[e])); s = fmaf(vv, vv, s); }
    Ve[j] = s;
}

// ---------------------------------------------------------------------------
// FM: 4 batch rows/block (512 blocks -> 2 blocks/CU), thread: 4 channels.
// ---------------------------------------------------------------------------
__global__ __launch_bounds__(256) void fm_kernel(
    const unsigned short* __restrict__ vb, const float* __restrict__ Ve,
    const float* __restrict__ lin_w, const float* __restrict__ lin_b,
    unsigned short* __restrict__ resb)
{
    __shared__ float xs[4][1032];
    const int r0 = blockIdx.x * 4;
    const int t  = threadIdx.x;

    #pragma unroll
    for (int r = 0; r < 4; ++r) {
        const ushort4 u = reinterpret_cast<const ushort4*>(resb + (size_t)(r0 + r) * 2048)[t];
        xs[r][t*4+0] = bf2f(u.x); xs[r][t*4+1] = bf2f(u.y);
        xs[r][t*4+2] = bf2f(u.z); xs[r][t*4+3] = bf2f(u.w);
    }
    if (t < 8) {
        #pragma unroll
        for (int r = 0; r < 4; ++r) xs[r][1024 + t] = 0.f;
    }
    __syncthreads();

    float lw[8];
    #pragma unroll
    for (int f = 0; f < 8; ++f) lw[f] = lin_w[f];
    const float lb = lin_b[0];

    const int ch0 = t * 4;
    float xw[4][12];
    #pragma unroll
    for (int r = 0; r < 4; ++r) {
        const float4 a = *reinterpret_cast<const float4*>(&xs[r][ch0]);
        const float4 b = *reinterpret_cast<const float4*>(&xs[r][ch0 + 4]);
        const float4 c = *reinterpret_cast<const float4*>(&xs[r][ch0 + 8]);
        xw[r][0]=a.x; xw[r][1]=a.y; xw[r][2]=a.z; xw[r][3]=a.w;
        xw[r][4]=b.x; xw[r][5]=b.y; xw[r][6]=b.z; xw[r][7]=b.w;
        xw[r][8]=c.x; xw[r][9]=c.y; xw[r][10]=c.z; xw[r][11]=c.w;
    }

    #pragma unroll
    for (int c = 0; c < 4; ++c) {
        const int ch = ch0 + c;
        float outv[4] = {0.f, 0.f, 0.f, 0.f};
        if (ch < 1017) {
            float lin[4], sos[4] = {0,0,0,0}, fmv[4] = {0,0,0,0};
            #pragma unroll
            for (int r = 0; r < 4; ++r) {
                float s = lb;
                #pragma unroll
                for (int f = 0; f < 8; ++f) s = fmaf(xw[r][c+f], lw[f], s);
                lin[r] = s;
            }
            #pragma unroll
            for (int f = 0; f < 8; ++f) {
                const float ve = Ve[ch * 8 + f];
                #pragma unroll
                for (int r = 0; r < 4; ++r)
                    sos[r] = fmaf(xw[r][c+f] * xw[r][c+f], ve, sos[r]);
            }
            const unsigned short* vp = vb + (size_t)ch * 128;
            #pragma unroll
            for (int qq = 0; qq < 4; ++qq) {
                float s[4][4];
                #pragma unroll
                for (int r = 0; r < 4; ++r)
                    #pragma unroll
                    for (int e = 0; e < 4; ++e) s[r][e] = 0.f;
                #pragma unroll
                for (int f = 0; f < 8; ++f) {
                    const ushort4 vv = *reinterpret_cast<const ushort4*>(vp + f * 16 + qq * 4);
                    const float v0 = bf2f(vv.x), v1 = bf2f(vv.y), v2 = bf2f(vv.z), v3 = bf2f(vv.w);
                    #pragma unroll
                    for (int r = 0; r < 4; ++r) {
                        const float xf = xw[r][c+f];
                        s[r][0] = fmaf(xf, v0, s[r][0]);
                        s[r][1] = fmaf(xf, v1, s[r][1]);
                        s[r][2] = fmaf(xf, v2, s[r][2]);
                        s[r][3] = fmaf(xf, v3, s[r][3]);
                    }
                }
                #pragma unroll
                for (int r = 0; r < 4; ++r)
                    fmv[r] += s[r][0]*s[r][0] + s[r][1]*s[r][1] + s[r][2]*s[r][2] + s[r][3]*s[r][3];
            }
            #pragma unroll
            for (int r = 0; r < 4; ++r) outv[r] = lin[r] + 0.5f * (fmv[r] - sos[r]);
        }
        #pragma unroll
        for (int r = 0; r < 4; ++r)
            resb[(size_t)(r0 + r) * 2048 + 1024 + ch] = f2bf(outv[r]);
    }
}

// Final: out[b] = sigmoid(sum_{i<32} part[i][b] + b2)
__global__ __launch_bounds__(64) void final2_kernel(
    const float* __restrict__ part, const float* __restrict__ b2,
    float* __restrict__ out)
{
    const int b = blockIdx.x * 64 + threadIdx.x;
    float s = b2[0];
    #pragma unroll
    for (int i = 0; i < 32; ++i) s += part[(size_t)i * 2048 + b];
    out[b] = 1.f / (1.f + expf(-s));
}

extern "C" void kernel_launch(void* const* d_in, const int* in_sizes, int n_in,
                              void* d_out, int out_size, void* d_ws, size_t ws_size,
                              hipStream_t stream)
{
    const float* dx = (const float*)d_in[0];
    const float* cx = (const float*)d_in[1];
    const float* Wd = (const float*)d_in[2];
    const float* bd = (const float*)d_in[3];
    const float* Wc = (const float*)d_in[4];
    const float* bc = (const float*)d_in[5];
    const float* v  = (const float*)d_in[6];
    const float* lw = (const float*)d_in[7];
    const float* lb = (const float*)d_in[8];
    const float* W1 = (const float*)d_in[9];
    const float* b1 = (const float*)d_in[10];
    const float* W2 = (const float*)d_in[11];
    const float* b2 = (const float*)d_in[12];
    float* out = (float*)d_out;

    char* ws = (char*)d_ws;
    unsigned short* resb = (unsigned short*)(ws);                              // 8 MB
    float*          part = (float*)(ws + (8u << 20));                          // 256 KB
    unsigned short* dxb  = (unsigned short*)(ws + (9u << 20));                 // 2 MB
    unsigned short* cxb  = (unsigned short*)(ws + (11u << 20));                // 1 MB
    unsigned short* WdT  = (unsigned short*)(ws + (12u << 20));                // 512 KB
    unsigned short* WcT  = (unsigned short*)(ws + (12u << 20) + (512u << 10)); // 256 KB
    unsigned short* W1T  = (unsigned short*)(ws + (13u << 20));                // 4 MB
    unsigned short* vb   = (unsigned short*)(ws + (17u << 20));                // 255 KB
    float*          Ve   = (float*)(ws + (17u << 20) + (320u << 10));          // 32 KB
    float*          b1p  = (float*)(ws + (17u << 20) + (384u << 10));          // 4 KB
    float*          W2p  = (float*)(ws + (17u << 20) + (388u << 10));          // 4 KB

    const int prep_blocks = 608 + (PREP_TOTAL + 255) / 256;
    hipLaunchKernelGGL(prep_all, dim3(prep_blocks), dim3(256), 0, stream,
                       dx, cx, v, b1, W2, Wd, Wc, W1,
                       dxb, cxb, vb, b1p, W2p, Ve, WdT, WcT, W1T);
    hipLaunchKernelGGL(gemm_top_mfma, dim3(256), dim3(512), 0, stream,
                       dxb, cxb, WdT, WcT, bd, bc, resb);
    hipLaunchKernelGGL(fm_kernel, dim3(512), dim3(256), 0, stream,
                       vb, Ve, lw, lb, resb);
    hipLaunchKernelGGL(gemm_w1_mfma, dim3(256), dim3(512), 0, stream,
                       resb, W1T, b1p, W2p, part);
    hipLaunchKernelGGL(final2_kernel, dim3(32), dim3(64), 0, stream,
                       part, b2, out);
}

// Round 7
// 65.535 us; speedup vs baseline: 1.0909x; 1.0909x over previous
//
#include <hip/hip_runtime.h>
#include <math.h>

// NDF=512 NCF=256 NCC=256 EMB=16 FIELD=8 B=2048
// NH0=1024 CHANNEL=1017 HID=1020 K3=2041
// resb: [2048][2048] bf16 (cols 0..1023 = x, 1024..2040 = x_fm2, 2041..2047 = 0)

typedef __bf16 bf16x8 __attribute__((ext_vector_type(8)));
typedef float  f32x4  __attribute__((ext_vector_type(4)));

__device__ __forceinline__ unsigned short f2bf(float x) {
    union { float f; unsigned u; } c; c.f = x;
    unsigned r = c.u + 0x7fffu + ((c.u >> 16) & 1u);
    return (unsigned short)(r >> 16);
}
__device__ __forceinline__ float bf2f(unsigned short u) {
    union { unsigned u; float f; } c; c.u = ((unsigned)u) << 16;
    return c.f;
}

#define GLDS(g, l) __builtin_amdgcn_global_load_lds( \
    (const __attribute__((address_space(1))) void*)(g), \
    (__attribute__((address_space(3))) void*)(l), 16, 0, 0)

// ---------------------------------------------------------------------------
// MFMA GEMM: C = act(A(bf16,MxK) @ B^T(bf16,[N][K]) + bias)
// BM=128 BN=64, K-step 128, 512 threads (8 waves).
// Quads split K within the tile (quad q: k-cols [64q,64q+64)); wave tile 64x32.
// 3-buffer LDS (144 KB), counted vmcnt(6) in steady state (stage of tile t
// has a full compute phase to land), one barrier per 128-K step.
// 256B rows, XOR swizzle elem ^= (row&7)<<3 on BOTH sides.
// Cross-quad acc reduction via LDS at the end.
// ---------------------------------------------------------------------------
template<int FUSE>   // FUSE 0: relu + bf16 store; FUSE 1: leaky + dot-W2 partials
__device__ __forceinline__ void mfma_gemm_body(
    const unsigned short* __restrict__ A, int lda,
    const unsigned short* __restrict__ B, int ldb,
    const float* __restrict__ bias,
    unsigned short* __restrict__ Cb, int ldc,                 // FUSE=0
    const float* __restrict__ W2p, float* __restrict__ part,  // FUSE=1
    int ccol0, int brow, int nbase, int K, int pcolb)
{
    __shared__ __align__(128) unsigned short As[3][128 * 128];  // 32KB x3
    __shared__ __align__(128) unsigned short Bs[3][64 * 128];   // 16KB x3

    const int t = threadIdx.x;
    const int w = t >> 6;
    const int l = t & 63;
    const int lr = l & 15, hi = l >> 4;
    const int lrx = (lr & 7) << 3;      // read-side swizzle XOR (elems)
    const int q   = w >> 2;             // k-half within the 128-K tile
    const int sub = w & 3;
    const int wr = sub >> 1, wc = sub & 1;
    const int kq = q << 6;              // quad k-elem base (0 or 64)

    f32x4 acc[4][2];
    #pragma unroll
    for (int m = 0; m < 4; ++m)
        #pragma unroll
        for (int n = 0; n < 2; ++n) acc[m][n] = f32x4{0.f, 0.f, 0.f, 0.f};

    const int nk = K >> 7;              // 128-K steps

    auto STAGE = [&](int buf, int k0) {
        #pragma unroll
        for (int i = 0; i < 4; ++i) {   // A: wave stages 16 rows (4 x 4-row instrs)
            const int r0 = w * 16 + i * 4;
            const int row = r0 + (l >> 4);
            const int se = ((l & 15) ^ (row & 7)) << 3;
            GLDS(A + (size_t)(brow + row) * lda + k0 + se, &As[buf][r0 * 128]);
        }
        #pragma unroll
        for (int i = 0; i < 2; ++i) {   // B: wave stages 8 rows
            const int r0 = w * 8 + i * 4;
            const int row = r0 + (l >> 4);
            const int se = ((l & 15) ^ (row & 7)) << 3;
            GLDS(B + (size_t)(nbase + row) * ldb + k0 + se, &Bs[buf][r0 * 128]);
        }
    };

    STAGE(0, 0);
    if (nk > 1) STAGE(1, 128);

    for (int tt = 0; tt < nk; ++tt) {
        // steady state: stage(tt) must be complete (12 outstanding -> wait to 6);
        // tail: drain everything.
        if (tt + 1 < nk) asm volatile("s_waitcnt vmcnt(6)" ::: "memory");
        else             asm volatile("s_waitcnt vmcnt(0)" ::: "memory");
        __builtin_amdgcn_s_barrier();
        if (tt + 2 < nk) STAGE((tt + 2) % 3, (tt + 2) << 7);

        const unsigned short* pa = &As[tt % 3][0];
        const unsigned short* pb = &Bs[tt % 3][0];
        bf16x8 af[4][2], bfv[2][2];
        #pragma unroll
        for (int m = 0; m < 4; ++m) {
            const int row = wr * 64 + m * 16 + lr;
            #pragma unroll
            for (int ks = 0; ks < 2; ++ks)
                af[m][ks] = *(const bf16x8*)&pa[row * 128 + ((kq + ks * 32 + hi * 8) ^ lrx)];
        }
        #pragma unroll
        for (int n = 0; n < 2; ++n) {
            const int row = wc * 32 + n * 16 + lr;
            #pragma unroll
            for (int ks = 0; ks < 2; ++ks)
                bfv[n][ks] = *(const bf16x8*)&pb[row * 128 + ((kq + ks * 32 + hi * 8) ^ lrx)];
        }
        #pragma unroll
        for (int ks = 0; ks < 2; ++ks)
            #pragma unroll
            for (int m = 0; m < 4; ++m)
                #pragma unroll
                for (int n = 0; n < 2; ++n)
                    acc[m][n] = __builtin_amdgcn_mfma_f32_16x16x32_bf16(af[m][ks], bfv[n][ks], acc[m][n], 0, 0, 0);
    }

    // Cross-quad reduction: quad1 writes accs to LDS (aliasing As), quad0 adds.
    __syncthreads();
    float* red = (float*)&As[0][0];     // 32 KB needed, 96 KB available
    if (q == 1) {
        #pragma unroll
        for (int m = 0; m < 4; ++m)
            #pragma unroll
            for (int n = 0; n < 2; ++n)
                *(f32x4*)&red[(((sub * 8) + m * 2 + n) * 64 + l) * 4] = acc[m][n];
    }
    __syncthreads();
    if (q != 0) return;

    #pragma unroll
    for (int m = 0; m < 4; ++m)
        #pragma unroll
        for (int n = 0; n < 2; ++n)
            acc[m][n] += *(const f32x4*)&red[(((sub * 8) + m * 2 + n) * 64 + l) * 4];

    // Epilogue. C/D map: col = lane&15, row = (lane>>4)*4 + j.
    const int orow0 = brow + wr * 64 + hi * 4;
    if (FUSE) {
        float bz[2], w2v[2];
        #pragma unroll
        for (int n = 0; n < 2; ++n) {
            const int col = ccol0 + wc * 32 + n * 16 + lr;
            bz[n] = bias[col];
            w2v[n] = W2p[col];
        }
        #pragma unroll
        for (int m = 0; m < 4; ++m) {
            #pragma unroll
            for (int j = 0; j < 4; ++j) {
                float p = 0.f;
                #pragma unroll
                for (int n = 0; n < 2; ++n) {
                    float z = acc[m][n][j] + bz[n];
                    z = (z > 0.f) ? z : 0.01f * z;
                    p = fmaf(z, w2v[n], p);
                }
                p += __shfl_xor(p, 1, 64);
                p += __shfl_xor(p, 2, 64);
                p += __shfl_xor(p, 4, 64);
                p += __shfl_xor(p, 8, 64);
                if (lr == 0)
                    part[(size_t)(pcolb + wc) * 2048 + orow0 + m * 16 + j] = p;
            }
        }
    } else {
        #pragma unroll
        for (int m = 0; m < 4; ++m) {
            #pragma unroll
            for (int n = 0; n < 2; ++n) {
                const int col = ccol0 + wc * 32 + n * 16 + lr;
                const float bz = bias[col];
                #pragma unroll
                for (int j = 0; j < 4; ++j) {
                    float z = acc[m][n][j] + bz;
                    z = fmaxf(z, 0.f);
                    Cb[(size_t)(orow0 + m * 16 + j) * ldc + col] = f2bf(z);
                }
            }
        }
    }
}

__global__ __launch_bounds__(512) void gemm_top_mfma(
    const unsigned short* __restrict__ dxb, const unsigned short* __restrict__ cxb,
    const unsigned short* __restrict__ WdT, const unsigned short* __restrict__ WcT,
    const float* __restrict__ bd, const float* __restrict__ bc,
    unsigned short* __restrict__ resb)
{
    const int bid = blockIdx.x;                   // 256 blocks
    const int swz = (bid & 7) * 32 + (bid >> 3);  // bijective XCD swizzle
    const int cb = swz & 15;
    const int brow = (swz >> 4) * 128;
    const int ccol0 = cb * 64;
    if (cb < 8)
        mfma_gemm_body<0>(dxb, 512, WdT, 512, bd, resb, 2048,
                          nullptr, nullptr, ccol0, brow, ccol0, 512, 0);
    else
        mfma_gemm_body<0>(cxb, 256, WcT, 256, bc - 512, resb, 2048,
                          nullptr, nullptr, ccol0, brow, ccol0 - 512, 256, 0);
}

__global__ __launch_bounds__(512) void gemm_w1_mfma(
    const unsigned short* __restrict__ resb, const unsigned short* __restrict__ W1T,
    const float* __restrict__ b1p, const float* __restrict__ W2p,
    float* __restrict__ part)
{
    const int bid = blockIdx.x;
    const int swz = (bid & 7) * 32 + (bid >> 3);
    const int cb = swz & 15;
    const int brow = (swz >> 4) * 128;
    mfma_gemm_body<1>(resb, 2048, W1T, 2048, b1p, nullptr, 0,
                      W2p, part, cb * 64, brow, cb * 64, 2048, cb * 2);
}

// ---------------------------------------------------------------------------
// prep_all: blocks 0..607 = transposes (Wd, Wc, W1 -> bf16 n-major);
//           blocks 608..  = elementwise prep (bf16 casts, pads, Gram G).
// G[ch][p] = sum_e v[ch][f][e]*v[ch][g][e] for pairs p=(f<g) in row-major
// (f outer, g inner) order; 28 pairs padded to 32 floats per channel.
// ---------------------------------------------------------------------------
#define N_DX (2048*512)
#define N_CX (2048*256)
#define PREP_TOTAL (N_DX + N_CX + 1024 + 1024 + 1017)

__global__ __launch_bounds__(256) void prep_all(
    const float* __restrict__ dx, const float* __restrict__ cx,
    const float* __restrict__ v,  const float* __restrict__ b1,
    const float* __restrict__ W2,
    const float* __restrict__ Wd, const float* __restrict__ Wc, const float* __restrict__ W1,
    unsigned short* __restrict__ dxb, unsigned short* __restrict__ cxb,
    float* __restrict__ b1p, float* __restrict__ W2p, float* __restrict__ G,
    unsigned short* __restrict__ WdT, unsigned short* __restrict__ WcT,
    unsigned short* __restrict__ W1T)
{
    __shared__ float tile[64][65];
    if (blockIdx.x < 608) {
        int bid = blockIdx.x;
        const float* in; unsigned short* out;
        int K0, N0, ldin, Kout, kt, nt;
        if (bid < 64) {
            in = Wd; out = WdT; K0 = 512; N0 = 512; ldin = 512; Kout = 512;
            kt = bid & 7; nt = bid >> 3;
        } else if (bid < 96) {
            bid -= 64;
            in = Wc; out = WcT; K0 = 256; N0 = 512; ldin = 512; Kout = 256;
            kt = bid & 3; nt = bid >> 2;
        } else {
            bid -= 96;
            in = W1; out = W1T; K0 = 2041; N0 = 1020; ldin = 1020; Kout = 2048;
            kt = bid & 31; nt = bid >> 5;
        }
        const int k0 = kt * 64, n0 = nt * 64;
        const int tt = threadIdx.x;
        const int nl = tt & 63, kq = tt >> 6;
        #pragma unroll
        for (int i = 0; i < 16; ++i) {
            const int kl = kq + i * 4;
            const int gk = k0 + kl, gn = n0 + nl;
            tile[kl][nl] = (gk < K0 && gn < N0) ? in[(size_t)gk * ldin + gn] : 0.f;
        }
        __syncthreads();
        const int kl2 = tt & 63, nq = tt >> 6;
        #pragma unroll
        for (int i = 0; i < 16; ++i) {
            const int nl2 = nq + i * 4;
            out[(size_t)(n0 + nl2) * Kout + k0 + kl2] = f2bf(tile[kl2][nl2]);
        }
        return;
    }
    int j = (blockIdx.x - 608) * 256 + threadIdx.x;
    if (j < N_DX) { dxb[j] = f2bf(dx[j]); return; }
    j -= N_DX;
    if (j < N_CX) { cxb[j] = f2bf(cx[j]); return; }
    j -= N_CX;
    if (j < 1024) { b1p[j] = (j < 1020) ? b1[j] : 0.f; return; }
    j -= 1024;
    if (j < 1024) { W2p[j] = (j < 1020) ? W2[j] : 0.f; return; }
    j -= 1024;
    if (j >= 1017) return;
    // Gram matrix for channel j
    const float* vp = v + (size_t)j * 128;
    float gacc[28];
    #pragma unroll
    for (int p = 0; p < 28; ++p) gacc[p] = 0.f;
    for (int e = 0; e < 16; ++e) {
        float vf[8];
        #pragma unroll
        for (int f = 0; f < 8; ++f) vf[f] = vp[f * 16 + e];
        int p = 0;
        #pragma unroll
        for (int f = 0; f < 8; ++f)
            #pragma unroll
            for (int g = f + 1; g < 8; ++g) { gacc[p] = fmaf(vf[f], vf[g], gacc[p]); ++p; }
    }
    #pragma unroll
    for (int p = 0; p < 28; ++p) G[(size_t)j * 32 + p] = gacc[p];
    #pragma unroll
    for (int p = 28; p < 32; ++p) G[(size_t)j * 32 + p] = 0.f;
}

// ---------------------------------------------------------------------------
// FM via Gram form: x_fm2[b,ch] = lin(b,ch) + sum_{f<g} x_f x_g G[ch][fg].
// 4 batch rows/block (512 blocks), thread: 4 consecutive channels.
// ---------------------------------------------------------------------------
__global__ __launch_bounds__(256) void fm_kernel(
    const float* __restrict__ G,
    const float* __restrict__ lin_w, const float* __restrict__ lin_b,
    unsigned short* __restrict__ resb)
{
    __shared__ float xs[4][1032];
    const int r0 = blockIdx.x * 4;
    const int t  = threadIdx.x;

    #pragma unroll
    for (int r = 0; r < 4; ++r) {
        const ushort4 u = reinterpret_cast<const ushort4*>(resb + (size_t)(r0 + r) * 2048)[t];
        xs[r][t*4+0] = bf2f(u.x); xs[r][t*4+1] = bf2f(u.y);
        xs[r][t*4+2] = bf2f(u.z); xs[r][t*4+3] = bf2f(u.w);
    }
    if (t < 8) {
        #pragma unroll
        for (int r = 0; r < 4; ++r) xs[r][1024 + t] = 0.f;
    }
    __syncthreads();

    float lw[8];
    #pragma unroll
    for (int f = 0; f < 8; ++f) lw[f] = lin_w[f];
    const float lb = lin_b[0];

    const int ch0 = t * 4;
    float xw[4][12];
    #pragma unroll
    for (int r = 0; r < 4; ++r) {
        const float4 a = *reinterpret_cast<const float4*>(&xs[r][ch0]);
        const float4 b = *reinterpret_cast<const float4*>(&xs[r][ch0 + 4]);
        const float4 c = *reinterpret_cast<const float4*>(&xs[r][ch0 + 8]);
        xw[r][0]=a.x; xw[r][1]=a.y; xw[r][2]=a.z; xw[r][3]=a.w;
        xw[r][4]=b.x; xw[r][5]=b.y; xw[r][6]=b.z; xw[r][7]=b.w;
        xw[r][8]=c.x; xw[r][9]=c.y; xw[r][10]=c.z; xw[r][11]=c.w;
    }

    #pragma unroll
    for (int c = 0; c < 4; ++c) {
        const int ch = ch0 + c;
        float outv[4] = {0.f, 0.f, 0.f, 0.f};
        if (ch < 1017) {
            f32x4 Gv[7];
            const float* gp = G + (size_t)ch * 32;
            #pragma unroll
            for (int i = 0; i < 7; ++i) Gv[i] = *reinterpret_cast<const f32x4*>(gp + i * 4);
            float lin[4], fmv[4] = {0.f, 0.f, 0.f, 0.f};
            #pragma unroll
            for (int r = 0; r < 4; ++r) {
                float s = lb;
                #pragma unroll
                for (int f = 0; f < 8; ++f) s = fmaf(xw[r][c+f], lw[f], s);
                lin[r] = s;
            }
            int p = 0;
            #pragma unroll
            for (int f = 0; f < 8; ++f) {
                #pragma unroll
                for (int g = f + 1; g < 8; ++g) {
                    const float gfg = Gv[p >> 2][p & 3];
                    #pragma unroll
                    for (int r = 0; r < 4; ++r)
                        fmv[r] = fmaf(xw[r][c+f] * xw[r][c+g], gfg, fmv[r]);
                    ++p;
                }
            }
            #pragma unroll
            for (int r = 0; r < 4; ++r) outv[r] = lin[r] + fmv[r];
        }
        #pragma unroll
        for (int r = 0; r < 4; ++r)
            resb[(size_t)(r0 + r) * 2048 + 1024 + ch] = f2bf(outv[r]);
    }
}

// Final: out[b] = sigmoid(sum_{i<32} part[i][b] + b2)
__global__ __launch_bounds__(64) void final2_kernel(
    const float* __restrict__ part, const float* __restrict__ b2,
    float* __restrict__ out)
{
    const int b = blockIdx.x * 64 + threadIdx.x;
    float s = b2[0];
    #pragma unroll
    for (int i = 0; i < 32; ++i) s += part[(size_t)i * 2048 + b];
    out[b] = 1.f / (1.f + expf(-s));
}

extern "C" void kernel_launch(void* const* d_in, const int* in_sizes, int n_in,
                              void* d_out, int out_size, void* d_ws, size_t ws_size,
                              hipStream_t stream)
{
    const float* dx = (const float*)d_in[0];
    const float* cx = (const float*)d_in[1];
    const float* Wd = (const float*)d_in[2];
    const float* bd = (const float*)d_in[3];
    const float* Wc = (const float*)d_in[4];
    const float* bc = (const float*)d_in[5];
    const float* v  = (const float*)d_in[6];
    const float* lw = (const float*)d_in[7];
    const float* lb = (const float*)d_in[8];
    const float* W1 = (const float*)d_in[9];
    const float* b1 = (const float*)d_in[10];
    const float* W2 = (const float*)d_in[11];
    const float* b2 = (const float*)d_in[12];
    float* out = (float*)d_out;

    char* ws = (char*)d_ws;
    unsigned short* resb = (unsigned short*)(ws);                              // 8 MB
    float*          part = (float*)(ws + (8u << 20));                          // 256 KB
    unsigned short* dxb  = (unsigned short*)(ws + (9u << 20));                 // 2 MB
    unsigned short* cxb  = (unsigned short*)(ws + (11u << 20));                // 1 MB
    unsigned short* WdT  = (unsigned short*)(ws + (12u << 20));                // 512 KB
    unsigned short* WcT  = (unsigned short*)(ws + (12u << 20) + (512u << 10)); // 256 KB
    unsigned short* W1T  = (unsigned short*)(ws + (13u << 20));                // 4 MB
    float*          G    = (float*)(ws + (17u << 20));                         // 132 KB
    float*          b1p  = (float*)(ws + (17u << 20) + (192u << 10));          // 4 KB
    float*          W2p  = (float*)(ws + (17u << 20) + (196u << 10));          // 4 KB

    const int prep_blocks = 608 + (PREP_TOTAL + 255) / 256;
    hipLaunchKernelGGL(prep_all, dim3(prep_blocks), dim3(256), 0, stream,
                       dx, cx, v, b1, W2, Wd, Wc, W1,
                       dxb, cxb, b1p, W2p, G, WdT, WcT, W1T);
    hipLaunchKernelGGL(gemm_top_mfma, dim3(256), dim3(512), 0, stream,
                       dxb, cxb, WdT, WcT, bd, bc, resb);
    hipLaunchKernelGGL(fm_kernel, dim3(512), dim3(256), 0, stream,
                       G, lw, lb, resb);
    hipLaunchKernelGGL(gemm_w1_mfma, dim3(256), dim3(512), 0, stream,
                       resb, W1T, b1p, W2p, part);
    hipLaunchKernelGGL(final2_kernel, dim3(32), dim3(64), 0, stream,
                       part, b2, out);
}

// Round 8
// 62.901 us; speedup vs baseline: 1.1365x; 1.0419x over previous
//
#include <hip/hip_runtime.h>
#include <math.h>

// NDF=512 NCF=256 NCC=256 EMB=16 FIELD=8 B=2048
// NH0=1024 CHANNEL=1017 HID=1020 K3=2041
// resb: [2048][2048] bf16 (cols 0..1023 = x, 1024..2040 = x_fm2, 2041..2047 = 0)

typedef __bf16 bf16x8 __attribute__((ext_vector_type(8)));
typedef float  f32x4  __attribute__((ext_vector_type(4)));

__device__ __forceinline__ unsigned short f2bf(float x) {
    union { float f; unsigned u; } c; c.f = x;
    unsigned r = c.u + 0x7fffu + ((c.u >> 16) & 1u);
    return (unsigned short)(r >> 16);
}
__device__ __forceinline__ float bf2f(unsigned short u) {
    union { unsigned u; float f; } c; c.u = ((unsigned)u) << 16;
    return c.f;
}

#define GLDS(g, l) __builtin_amdgcn_global_load_lds( \
    (const __attribute__((address_space(1))) void*)(g), \
    (__attribute__((address_space(3))) void*)(l), 16, 0, 0)

// ---------------------------------------------------------------------------
// MFMA GEMM: C = act(A(bf16,MxK) @ B^T(bf16,[N][K]) + bias)
// BM=128 BN=64, K-step 128, 512 threads (8 waves).
// Quads split K within the tile (quad q: k-cols [64q,64q+64)); wave tile 64x32.
// 3-buffer LDS (144 KB), counted vmcnt(6) in steady state, one barrier/K-step.
// 256B rows, XOR swizzle elem ^= (row&7)<<3 on BOTH sides.
// Cross-quad acc reduction via LDS at the end.
// ---------------------------------------------------------------------------
template<int FUSE>   // FUSE 0: relu + bf16 store; FUSE 1: leaky + dot-W2 partials
__device__ __forceinline__ void mfma_gemm_body(
    const unsigned short* __restrict__ A, int lda,
    const unsigned short* __restrict__ B, int ldb,
    const float* __restrict__ bias,
    unsigned short* __restrict__ Cb, int ldc,                 // FUSE=0
    const float* __restrict__ W2p, float* __restrict__ part,  // FUSE=1
    int ccol0, int brow, int nbase, int K, int pcolb)
{
    __shared__ __align__(128) unsigned short As[3][128 * 128];  // 32KB x3
    __shared__ __align__(128) unsigned short Bs[3][64 * 128];   // 16KB x3

    const int t = threadIdx.x;
    const int w = t >> 6;
    const int l = t & 63;
    const int lr = l & 15, hi = l >> 4;
    const int lrx = (lr & 7) << 3;      // read-side swizzle XOR (elems)
    const int q   = w >> 2;             // k-half within the 128-K tile
    const int sub = w & 3;
    const int wr = sub >> 1, wc = sub & 1;
    const int kq = q << 6;              // quad k-elem base (0 or 64)

    f32x4 acc[4][2];
    #pragma unroll
    for (int m = 0; m < 4; ++m)
        #pragma unroll
        for (int n = 0; n < 2; ++n) acc[m][n] = f32x4{0.f, 0.f, 0.f, 0.f};

    const int nk = K >> 7;              // 128-K steps

    auto STAGE = [&](int buf, int k0) {
        #pragma unroll
        for (int i = 0; i < 4; ++i) {   // A: wave stages 16 rows (4 x 4-row instrs)
            const int r0 = w * 16 + i * 4;
            const int row = r0 + (l >> 4);
            const int se = ((l & 15) ^ (row & 7)) << 3;
            GLDS(A + (size_t)(brow + row) * lda + k0 + se, &As[buf][r0 * 128]);
        }
        #pragma unroll
        for (int i = 0; i < 2; ++i) {   // B: wave stages 8 rows
            const int r0 = w * 8 + i * 4;
            const int row = r0 + (l >> 4);
            const int se = ((l & 15) ^ (row & 7)) << 3;
            GLDS(B + (size_t)(nbase + row) * ldb + k0 + se, &Bs[buf][r0 * 128]);
        }
    };

    STAGE(0, 0);
    if (nk > 1) STAGE(1, 128);

    for (int tt = 0; tt < nk; ++tt) {
        if (tt + 1 < nk) asm volatile("s_waitcnt vmcnt(6)" ::: "memory");
        else             asm volatile("s_waitcnt vmcnt(0)" ::: "memory");
        __builtin_amdgcn_s_barrier();
        if (tt + 2 < nk) STAGE((tt + 2) % 3, (tt + 2) << 7);

        const unsigned short* pa = &As[tt % 3][0];
        const unsigned short* pb = &Bs[tt % 3][0];
        bf16x8 af[4][2], bfv[2][2];
        #pragma unroll
        for (int m = 0; m < 4; ++m) {
            const int row = wr * 64 + m * 16 + lr;
            #pragma unroll
            for (int ks = 0; ks < 2; ++ks)
                af[m][ks] = *(const bf16x8*)&pa[row * 128 + ((kq + ks * 32 + hi * 8) ^ lrx)];
        }
        #pragma unroll
        for (int n = 0; n < 2; ++n) {
            const int row = wc * 32 + n * 16 + lr;
            #pragma unroll
            for (int ks = 0; ks < 2; ++ks)
                bfv[n][ks] = *(const bf16x8*)&pb[row * 128 + ((kq + ks * 32 + hi * 8) ^ lrx)];
        }
        #pragma unroll
        for (int ks = 0; ks < 2; ++ks)
            #pragma unroll
            for (int m = 0; m < 4; ++m)
                #pragma unroll
                for (int n = 0; n < 2; ++n)
                    acc[m][n] = __builtin_amdgcn_mfma_f32_16x16x32_bf16(af[m][ks], bfv[n][ks], acc[m][n], 0, 0, 0);
    }

    // Cross-quad reduction: quad1 writes accs to LDS (aliasing As), quad0 adds.
    __syncthreads();
    float* red = (float*)&As[0][0];
    if (q == 1) {
        #pragma unroll
        for (int m = 0; m < 4; ++m)
            #pragma unroll
            for (int n = 0; n < 2; ++n)
                *(f32x4*)&red[(((sub * 8) + m * 2 + n) * 64 + l) * 4] = acc[m][n];
    }
    __syncthreads();
    if (q != 0) return;

    #pragma unroll
    for (int m = 0; m < 4; ++m)
        #pragma unroll
        for (int n = 0; n < 2; ++n)
            acc[m][n] += *(const f32x4*)&red[(((sub * 8) + m * 2 + n) * 64 + l) * 4];

    // Epilogue. C/D map: col = lane&15, row = (lane>>4)*4 + j.
    const int orow0 = brow + wr * 64 + hi * 4;
    if (FUSE) {
        float bz[2], w2v[2];
        #pragma unroll
        for (int n = 0; n < 2; ++n) {
            const int col = ccol0 + wc * 32 + n * 16 + lr;
            bz[n] = bias[col];
            w2v[n] = W2p[col];
        }
        #pragma unroll
        for (int m = 0; m < 4; ++m) {
            #pragma unroll
            for (int j = 0; j < 4; ++j) {
                float p = 0.f;
                #pragma unroll
                for (int n = 0; n < 2; ++n) {
                    float z = acc[m][n][j] + bz[n];
                    z = (z > 0.f) ? z : 0.01f * z;
                    p = fmaf(z, w2v[n], p);
                }
                p += __shfl_xor(p, 1, 64);
                p += __shfl_xor(p, 2, 64);
                p += __shfl_xor(p, 4, 64);
                p += __shfl_xor(p, 8, 64);
                if (lr == 0)
                    part[(size_t)(pcolb + wc) * 2048 + orow0 + m * 16 + j] = p;
            }
        }
    } else {
        #pragma unroll
        for (int m = 0; m < 4; ++m) {
            #pragma unroll
            for (int n = 0; n < 2; ++n) {
                const int col = ccol0 + wc * 32 + n * 16 + lr;
                const float bz = bias[col];
                #pragma unroll
                for (int j = 0; j < 4; ++j) {
                    float z = acc[m][n][j] + bz;
                    z = fmaxf(z, 0.f);
                    Cb[(size_t)(orow0 + m * 16 + j) * ldc + col] = f2bf(z);
                }
            }
        }
    }
}

__global__ __launch_bounds__(512) void gemm_top_mfma(
    const unsigned short* __restrict__ dxb, const unsigned short* __restrict__ cxb,
    const unsigned short* __restrict__ WdT, const unsigned short* __restrict__ WcT,
    const float* __restrict__ bd, const float* __restrict__ bc,
    unsigned short* __restrict__ resb)
{
    const int bid = blockIdx.x;                   // 256 blocks
    const int swz = (bid & 7) * 32 + (bid >> 3);  // bijective XCD swizzle
    const int cb = swz & 15;
    const int brow = (swz >> 4) * 128;
    const int ccol0 = cb * 64;
    if (cb < 8)
        mfma_gemm_body<0>(dxb, 512, WdT, 512, bd, resb, 2048,
                          nullptr, nullptr, ccol0, brow, ccol0, 512, 0);
    else
        mfma_gemm_body<0>(cxb, 256, WcT, 256, bc - 512, resb, 2048,
                          nullptr, nullptr, ccol0, brow, ccol0 - 512, 256, 0);
}

__global__ __launch_bounds__(512) void gemm_w1_mfma(
    const unsigned short* __restrict__ resb, const unsigned short* __restrict__ W1T,
    const float* __restrict__ b1p, const float* __restrict__ W2p,
    float* __restrict__ part)
{
    const int bid = blockIdx.x;
    const int swz = (bid & 7) * 32 + (bid >> 3);
    const int cb = swz & 15;
    const int brow = (swz >> 4) * 128;
    mfma_gemm_body<1>(resb, 2048, W1T, 2048, b1p, nullptr, 0,
                      W2p, part, cb * 64, brow, cb * 64, 2048, cb * 2);
}

// ---------------------------------------------------------------------------
// prep_a: only what gemm_top + fm need.
// blocks 0..63  : Wd transpose -> WdT (bf16 [512][512])
// blocks 64..95 : Wc transpose -> WcT (bf16 [512][256])
// blocks 96..   : dx/cx casts, b1p/W2p pads, Gram G
// ---------------------------------------------------------------------------
#define N_DX (2048*512)
#define N_CX (2048*256)
#define PREP_A_ELEMS (N_DX + N_CX + 1024 + 1024 + 1017)

__global__ __launch_bounds__(256) void prep_a(
    const float* __restrict__ dx, const float* __restrict__ cx,
    const float* __restrict__ v,  const float* __restrict__ b1,
    const float* __restrict__ W2,
    const float* __restrict__ Wd, const float* __restrict__ Wc,
    unsigned short* __restrict__ dxb, unsigned short* __restrict__ cxb,
    float* __restrict__ b1p, float* __restrict__ W2p, float* __restrict__ G,
    unsigned short* __restrict__ WdT, unsigned short* __restrict__ WcT)
{
    __shared__ float tile[64][65];
    if (blockIdx.x < 96) {
        int bid = blockIdx.x;
        const float* in; unsigned short* out;
        int ldin, Kout, kt, nt;
        if (bid < 64) { in = Wd; out = WdT; ldin = 512; Kout = 512; kt = bid & 7; nt = bid >> 3; }
        else { bid -= 64; in = Wc; out = WcT; ldin = 512; Kout = 256; kt = bid & 3; nt = bid >> 2; }
        const int k0 = kt * 64, n0 = nt * 64;
        const int tt = threadIdx.x;
        const int nl = tt & 63, kq = tt >> 6;
        #pragma unroll
        for (int i = 0; i < 16; ++i)
            tile[kq + i * 4][nl] = in[(size_t)(k0 + kq + i * 4) * ldin + n0 + nl];
        __syncthreads();
        const int kl2 = tt & 63, nq = tt >> 6;
        #pragma unroll
        for (int i = 0; i < 16; ++i)
            out[(size_t)(n0 + nq + i * 4) * Kout + k0 + kl2] = f2bf(tile[kl2][nq + i * 4]);
        return;
    }
    int j = (blockIdx.x - 96) * 256 + threadIdx.x;
    if (j < N_DX) { dxb[j] = f2bf(dx[j]); return; }
    j -= N_DX;
    if (j < N_CX) { cxb[j] = f2bf(cx[j]); return; }
    j -= N_CX;
    if (j < 1024) { b1p[j] = (j < 1020) ? b1[j] : 0.f; return; }
    j -= 1024;
    if (j < 1024) { W2p[j] = (j < 1020) ? W2[j] : 0.f; return; }
    j -= 1024;
    if (j >= 1017) return;
    // Gram matrix for channel j: G[j][p] = sum_e v[j][f][e]*v[j][g][e], f<g
    const float* vp = v + (size_t)j * 128;
    float gacc[28];
    #pragma unroll
    for (int p = 0; p < 28; ++p) gacc[p] = 0.f;
    for (int e = 0; e < 16; ++e) {
        float vf[8];
        #pragma unroll
        for (int f = 0; f < 8; ++f) vf[f] = vp[f * 16 + e];
        int p = 0;
        #pragma unroll
        for (int f = 0; f < 8; ++f)
            #pragma unroll
            for (int g = f + 1; g < 8; ++g) { gacc[p] = fmaf(vf[f], vf[g], gacc[p]); ++p; }
    }
    #pragma unroll
    for (int p = 0; p < 28; ++p) G[(size_t)j * 32 + p] = gacc[p];
    #pragma unroll
    for (int p = 28; p < 32; ++p) G[(size_t)j * 32 + p] = 0.f;
}

// ---------------------------------------------------------------------------
// fm_w1t: blocks 0..511 = FM (Gram form, 4 rows/block);
//         blocks 512..1023 = W1 transpose (independent, hides under fm).
// ---------------------------------------------------------------------------
__global__ __launch_bounds__(256) void fm_w1t(
    const float* __restrict__ G,
    const float* __restrict__ lin_w, const float* __restrict__ lin_b,
    unsigned short* __restrict__ resb,
    const float* __restrict__ W1, unsigned short* __restrict__ W1T)
{
    if (blockIdx.x >= 512) {
        // W1[2041][1020] -> W1T[1024][2048] bf16, zero-padded
        __shared__ float tile[64][65];
        const int bid = blockIdx.x - 512;       // 0..511
        const int kt = bid & 31, nt = bid >> 5; // 32 x 16
        const int k0 = kt * 64, n0 = nt * 64;
        const int tt = threadIdx.x;
        const int nl = tt & 63, kq = tt >> 6;
        #pragma unroll
        for (int i = 0; i < 16; ++i) {
            const int kl = kq + i * 4;
            const int gk = k0 + kl, gn = n0 + nl;
            tile[kl][nl] = (gk < 2041 && gn < 1020) ? W1[(size_t)gk * 1020 + gn] : 0.f;
        }
        __syncthreads();
        const int kl2 = tt & 63, nq = tt >> 6;
        #pragma unroll
        for (int i = 0; i < 16; ++i) {
            const int nl2 = nq + i * 4;
            W1T[(size_t)(n0 + nl2) * 2048 + k0 + kl2] = f2bf(tile[kl2][nl2]);
        }
        return;
    }

    __shared__ float xs[4][1032];
    const int r0 = blockIdx.x * 4;
    const int t  = threadIdx.x;

    #pragma unroll
    for (int r = 0; r < 4; ++r) {
        const ushort4 u = reinterpret_cast<const ushort4*>(resb + (size_t)(r0 + r) * 2048)[t];
        xs[r][t*4+0] = bf2f(u.x); xs[r][t*4+1] = bf2f(u.y);
        xs[r][t*4+2] = bf2f(u.z); xs[r][t*4+3] = bf2f(u.w);
    }
    if (t < 8) {
        #pragma unroll
        for (int r = 0; r < 4; ++r) xs[r][1024 + t] = 0.f;
    }
    __syncthreads();

    float lw[8];
    #pragma unroll
    for (int f = 0; f < 8; ++f) lw[f] = lin_w[f];
    const float lb = lin_b[0];

    const int ch0 = t * 4;
    float xw[4][12];
    #pragma unroll
    for (int r = 0; r < 4; ++r) {
        const float4 a = *reinterpret_cast<const float4*>(&xs[r][ch0]);
        const float4 b = *reinterpret_cast<const float4*>(&xs[r][ch0 + 4]);
        const float4 c = *reinterpret_cast<const float4*>(&xs[r][ch0 + 8]);
        xw[r][0]=a.x; xw[r][1]=a.y; xw[r][2]=a.z; xw[r][3]=a.w;
        xw[r][4]=b.x; xw[r][5]=b.y; xw[r][6]=b.z; xw[r][7]=b.w;
        xw[r][8]=c.x; xw[r][9]=c.y; xw[r][10]=c.z; xw[r][11]=c.w;
    }

    #pragma unroll
    for (int c = 0; c < 4; ++c) {
        const int ch = ch0 + c;
        float outv[4] = {0.f, 0.f, 0.f, 0.f};
        if (ch < 1017) {
            f32x4 Gv[7];
            const float* gp = G + (size_t)ch * 32;
            #pragma unroll
            for (int i = 0; i < 7; ++i) Gv[i] = *reinterpret_cast<const f32x4*>(gp + i * 4);
            float lin[4], fmv[4] = {0.f, 0.f, 0.f, 0.f};
            #pragma unroll
            for (int r = 0; r < 4; ++r) {
                float s = lb;
                #pragma unroll
                for (int f = 0; f < 8; ++f) s = fmaf(xw[r][c+f], lw[f], s);
                lin[r] = s;
            }
            int p = 0;
            #pragma unroll
            for (int f = 0; f < 8; ++f) {
                #pragma unroll
                for (int g = f + 1; g < 8; ++g) {
                    const float gfg = Gv[p >> 2][p & 3];
                    #pragma unroll
                    for (int r = 0; r < 4; ++r)
                        fmv[r] = fmaf(xw[r][c+f] * xw[r][c+g], gfg, fmv[r]);
                    ++p;
                }
            }
            #pragma unroll
            for (int r = 0; r < 4; ++r) outv[r] = lin[r] + fmv[r];
        }
        #pragma unroll
        for (int r = 0; r < 4; ++r)
            resb[(size_t)(r0 + r) * 2048 + 1024 + ch] = f2bf(outv[r]);
    }
}

// Final: out[b] = sigmoid(sum_{i<32} part[i][b] + b2)
__global__ __launch_bounds__(64) void final2_kernel(
    const float* __restrict__ part, const float* __restrict__ b2,
    float* __restrict__ out)
{
    const int b = blockIdx.x * 64 + threadIdx.x;
    float s = b2[0];
    #pragma unroll
    for (int i = 0; i < 32; ++i) s += part[(size_t)i * 2048 + b];
    out[b] = 1.f / (1.f + expf(-s));
}

extern "C" void kernel_launch(void* const* d_in, const int* in_sizes, int n_in,
                              void* d_out, int out_size, void* d_ws, size_t ws_size,
                              hipStream_t stream)
{
    const float* dx = (const float*)d_in[0];
    const float* cx = (const float*)d_in[1];
    const float* Wd = (const float*)d_in[2];
    const float* bd = (const float*)d_in[3];
    const float* Wc = (const float*)d_in[4];
    const float* bc = (const float*)d_in[5];
    const float* v  = (const float*)d_in[6];
    const float* lw = (const float*)d_in[7];
    const float* lb = (const float*)d_in[8];
    const float* W1 = (const float*)d_in[9];
    const float* b1 = (const float*)d_in[10];
    const float* W2 = (const float*)d_in[11];
    const float* b2 = (const float*)d_in[12];
    float* out = (float*)d_out;

    char* ws = (char*)d_ws;
    unsigned short* resb = (unsigned short*)(ws);                              // 8 MB
    float*          part = (float*)(ws + (8u << 20));                          // 256 KB
    unsigned short* dxb  = (unsigned short*)(ws + (9u << 20));                 // 2 MB
    unsigned short* cxb  = (unsigned short*)(ws + (11u << 20));                // 1 MB
    unsigned short* WdT  = (unsigned short*)(ws + (12u << 20));                // 512 KB
    unsigned short* WcT  = (unsigned short*)(ws + (12u << 20) + (512u << 10)); // 256 KB
    unsigned short* W1T  = (unsigned short*)(ws + (13u << 20));                // 4 MB
    float*          G    = (float*)(ws + (17u << 20));                         // 132 KB
    float*          b1p  = (float*)(ws + (17u << 20) + (192u << 10));          // 4 KB
    float*          W2p  = (float*)(ws + (17u << 20) + (196u << 10));          // 4 KB

    const int prep_a_blocks = 96 + (PREP_A_ELEMS + 255) / 256;
    hipLaunchKernelGGL(prep_a, dim3(prep_a_blocks), dim3(256), 0, stream,
                       dx, cx, v, b1, W2, Wd, Wc,
                       dxb, cxb, b1p, W2p, G, WdT, WcT);
    hipLaunchKernelGGL(gemm_top_mfma, dim3(256), dim3(512), 0, stream,
                       dxb, cxb, WdT, WcT, bd, bc, resb);
    hipLaunchKernelGGL(fm_w1t, dim3(1024), dim3(256), 0, stream,
                       G, lw, lb, resb, W1, W1T);
    hipLaunchKernelGGL(gemm_w1_mfma, dim3(256), dim3(512), 0, stream,
                       resb, W1T, b1p, W2p, part);
    hipLaunchKernelGGL(final2_kernel, dim3(32), dim3(64), 0, stream,
                       part, b2, out);
}

// Round 9
// 61.115 us; speedup vs baseline: 1.1697x; 1.0292x over previous
//
#include <hip/hip_runtime.h>
#include <math.h>

// NDF=512 NCF=256 NCC=256 EMB=16 FIELD=8 B=2048
// NH0=1024 CHANNEL=1017 HID=1020 K3=2041
// resb: [2048][2048] bf16 (cols 0..1023 = x, 1024..2040 = x_fm2, 2041..2047 = 0)

typedef __bf16 bf16x8 __attribute__((ext_vector_type(8)));
typedef float  f32x4  __attribute__((ext_vector_type(4)));

__device__ __forceinline__ unsigned short f2bf(float x) {
    union { float f; unsigned u; } c; c.f = x;
    unsigned r = c.u + 0x7fffu + ((c.u >> 16) & 1u);
    return (unsigned short)(r >> 16);
}
__device__ __forceinline__ float bf2f(unsigned short u) {
    union { unsigned u; float f; } c; c.u = ((unsigned)u) << 16;
    return c.f;
}

#define GLDS(g, l) __builtin_amdgcn_global_load_lds( \
    (const __attribute__((address_space(1))) void*)(g), \
    (__attribute__((address_space(3))) void*)(l), 16, 0, 0)

// ---------------------------------------------------------------------------
// GEMM body A (for gemm_top): BM=128 BN=64 Kstep=128, 8 waves,
// 2-way K-split (quads), wave tile 64x32, 3-buffer vmcnt(6). (round-8 proven)
// ---------------------------------------------------------------------------
__device__ __forceinline__ void gemm_body_top(
    const unsigned short* __restrict__ A, int lda,
    const unsigned short* __restrict__ B, int ldb,
    const float* __restrict__ bias,
    unsigned short* __restrict__ Cb, int ldc,
    int ccol0, int brow, int nbase, int K)
{
    __shared__ __align__(128) unsigned short As[3][128 * 128];
    __shared__ __align__(128) unsigned short Bs[3][64 * 128];

    const int t = threadIdx.x;
    const int w = t >> 6;
    const int l = t & 63;
    const int lr = l & 15, hi = l >> 4;
    const int lrx = (lr & 7) << 3;
    const int q   = w >> 2;
    const int sub = w & 3;
    const int wr = sub >> 1, wc = sub & 1;
    const int kq = q << 6;

    f32x4 acc[4][2];
    #pragma unroll
    for (int m = 0; m < 4; ++m)
        #pragma unroll
        for (int n = 0; n < 2; ++n) acc[m][n] = f32x4{0.f, 0.f, 0.f, 0.f};

    const int nk = K >> 7;

    auto STAGE = [&](int buf, int k0) {
        #pragma unroll
        for (int i = 0; i < 4; ++i) {
            const int r0 = w * 16 + i * 4;
            const int row = r0 + (l >> 4);
            const int se = ((l & 15) ^ (row & 7)) << 3;
            GLDS(A + (size_t)(brow + row) * lda + k0 + se, &As[buf][r0 * 128]);
        }
        #pragma unroll
        for (int i = 0; i < 2; ++i) {
            const int r0 = w * 8 + i * 4;
            const int row = r0 + (l >> 4);
            const int se = ((l & 15) ^ (row & 7)) << 3;
            GLDS(B + (size_t)(nbase + row) * ldb + k0 + se, &Bs[buf][r0 * 128]);
        }
    };

    STAGE(0, 0);
    if (nk > 1) STAGE(1, 128);

    for (int tt = 0; tt < nk; ++tt) {
        if (tt + 1 < nk) asm volatile("s_waitcnt vmcnt(6)" ::: "memory");
        else             asm volatile("s_waitcnt vmcnt(0)" ::: "memory");
        __builtin_amdgcn_s_barrier();
        if (tt + 2 < nk) STAGE((tt + 2) % 3, (tt + 2) << 7);

        const unsigned short* pa = &As[tt % 3][0];
        const unsigned short* pb = &Bs[tt % 3][0];
        bf16x8 af[4][2], bfv[2][2];
        #pragma unroll
        for (int m = 0; m < 4; ++m) {
            const int row = wr * 64 + m * 16 + lr;
            #pragma unroll
            for (int ks = 0; ks < 2; ++ks)
                af[m][ks] = *(const bf16x8*)&pa[row * 128 + ((kq + ks * 32 + hi * 8) ^ lrx)];
        }
        #pragma unroll
        for (int n = 0; n < 2; ++n) {
            const int row = wc * 32 + n * 16 + lr;
            #pragma unroll
            for (int ks = 0; ks < 2; ++ks)
                bfv[n][ks] = *(const bf16x8*)&pb[row * 128 + ((kq + ks * 32 + hi * 8) ^ lrx)];
        }
        #pragma unroll
        for (int ks = 0; ks < 2; ++ks)
            #pragma unroll
            for (int m = 0; m < 4; ++m)
                #pragma unroll
                for (int n = 0; n < 2; ++n)
                    acc[m][n] = __builtin_amdgcn_mfma_f32_16x16x32_bf16(af[m][ks], bfv[n][ks], acc[m][n], 0, 0, 0);
    }

    __syncthreads();
    float* red = (float*)&As[0][0];
    if (q == 1) {
        #pragma unroll
        for (int m = 0; m < 4; ++m)
            #pragma unroll
            for (int n = 0; n < 2; ++n)
                *(f32x4*)&red[(((sub * 8) + m * 2 + n) * 64 + l) * 4] = acc[m][n];
    }
    __syncthreads();
    if (q != 0) return;

    #pragma unroll
    for (int m = 0; m < 4; ++m)
        #pragma unroll
        for (int n = 0; n < 2; ++n)
            acc[m][n] += *(const f32x4*)&red[(((sub * 8) + m * 2 + n) * 64 + l) * 4];

    const int orow0 = brow + wr * 64 + hi * 4;
    #pragma unroll
    for (int m = 0; m < 4; ++m) {
        #pragma unroll
        for (int n = 0; n < 2; ++n) {
            const int col = ccol0 + wc * 32 + n * 16 + lr;
            const float bz = bias[col];
            #pragma unroll
            for (int j = 0; j < 4; ++j) {
                float z = acc[m][n][j] + bz;
                z = fmaxf(z, 0.f);
                Cb[(size_t)(orow0 + m * 16 + j) * ldc + col] = f2bf(z);
            }
        }
    }
}

__global__ __launch_bounds__(512) void gemm_top_mfma(
    const unsigned short* __restrict__ dxb, const unsigned short* __restrict__ cxb,
    const unsigned short* __restrict__ WdT, const unsigned short* __restrict__ WcT,
    const float* __restrict__ bd, const float* __restrict__ bc,
    unsigned short* __restrict__ resb)
{
    const int bid = blockIdx.x;                   // 256 blocks
    const int swz = (bid & 7) * 32 + (bid >> 3);  // bijective XCD swizzle
    const int cb = swz & 15;
    const int brow = (swz >> 4) * 128;
    const int ccol0 = cb * 64;
    if (cb < 8)
        gemm_body_top(dxb, 512, WdT, 512, bd, resb, 2048, ccol0, brow, ccol0, 512);
    else
        gemm_body_top(cxb, 256, WcT, 256, bc - 512, resb, 2048, ccol0, brow, ccol0 - 512, 256);
}

// ---------------------------------------------------------------------------
// GEMM body B (gemm_w1): BM=128 BN=64 Kstep=128, 8 waves = 2 m-tiles x 4-way
// K-split, wave tile 64x64 (acc[4][4]) -> 8 ds_read per 16 MFMA (2x fewer
// LDS bytes/flop than body A). 3-buffer vmcnt(6). 4-way cross-quad LDS
// reduction, then fused leaky+dot-W2 epilogue -> part[16][2048].
// ---------------------------------------------------------------------------
__global__ __launch_bounds__(512) void gemm_w1_mfma(
    const unsigned short* __restrict__ Ab, const unsigned short* __restrict__ Bb,
    const float* __restrict__ b1p, const float* __restrict__ W2p,
    float* __restrict__ part)
{
    __shared__ __align__(128) unsigned short As[3][128 * 128];  // 96 KB
    __shared__ __align__(128) unsigned short Bs[3][64 * 128];   // 48 KB

    const int bid = blockIdx.x;
    const int swz = (bid & 7) * 32 + (bid >> 3);
    const int cb = swz & 15;
    const int brow = (swz >> 4) * 128;
    const int nbase = cb * 64;
    const int ccol0 = cb * 64;
    const int lda = 2048, ldb = 2048;
    const int K = 2048;

    const int t = threadIdx.x;
    const int w = t >> 6;
    const int l = t & 63;
    const int lr = l & 15, hi = l >> 4;
    const int lrx = (lr & 7) << 3;
    const int tl = w & 1;           // m-tile (rows tl*64)
    const int q  = w >> 1;          // k-quad (k-cols [32q, 32q+32) of the step)
    const int kq = q << 5;

    f32x4 acc[4][4];
    #pragma unroll
    for (int m = 0; m < 4; ++m)
        #pragma unroll
        for (int n = 0; n < 4; ++n) acc[m][n] = f32x4{0.f, 0.f, 0.f, 0.f};

    const int nk = K >> 7;          // 16

    auto STAGE = [&](int buf, int k0) {
        #pragma unroll
        for (int i = 0; i < 4; ++i) {
            const int r0 = w * 16 + i * 4;
            const int row = r0 + (l >> 4);
            const int se = ((l & 15) ^ (row & 7)) << 3;
            GLDS(Ab + (size_t)(brow + row) * lda + k0 + se, &As[buf][r0 * 128]);
        }
        #pragma unroll
        for (int i = 0; i < 2; ++i) {
            const int r0 = w * 8 + i * 4;
            const int row = r0 + (l >> 4);
            const int se = ((l & 15) ^ (row & 7)) << 3;
            GLDS(Bb + (size_t)(nbase + row) * ldb + k0 + se, &Bs[buf][r0 * 128]);
        }
    };

    STAGE(0, 0);
    STAGE(1, 128);

    for (int tt = 0; tt < nk; ++tt) {
        if (tt + 1 < nk) asm volatile("s_waitcnt vmcnt(6)" ::: "memory");
        else             asm volatile("s_waitcnt vmcnt(0)" ::: "memory");
        __builtin_amdgcn_s_barrier();
        if (tt + 2 < nk) STAGE((tt + 2) % 3, (tt + 2) << 7);

        const unsigned short* pa = &As[tt % 3][0];
        const unsigned short* pb = &Bs[tt % 3][0];
        bf16x8 af[4], bfv[4];
        #pragma unroll
        for (int m = 0; m < 4; ++m) {
            const int row = tl * 64 + m * 16 + lr;
            af[m] = *(const bf16x8*)&pa[row * 128 + ((kq + hi * 8) ^ lrx)];
        }
        #pragma unroll
        for (int n = 0; n < 4; ++n) {
            const int row = n * 16 + lr;
            bfv[n] = *(const bf16x8*)&pb[row * 128 + ((kq + hi * 8) ^ lrx)];
        }
        #pragma unroll
        for (int m = 0; m < 4; ++m)
            #pragma unroll
            for (int n = 0; n < 4; ++n)
                acc[m][n] = __builtin_amdgcn_mfma_f32_16x16x32_bf16(af[m], bfv[n], acc[m][n], 0, 0, 0);
    }

    // Cross-quad reduction: quads 1..3 write 64 f32/lane; quad 0 accumulates.
    // Slot (q-1, tl): base f32 = ((q-1)*2 + tl) * 4096; chunk c = m*4+n.
    __syncthreads();
    float* red = (float*)&As[0][0];   // 96 KB needed, 96 KB available
    if (q != 0) {
        const int base = ((q - 1) * 2 + tl) * 4096;
        #pragma unroll
        for (int m = 0; m < 4; ++m)
            #pragma unroll
            for (int n = 0; n < 4; ++n)
                *(f32x4*)&red[base + (((m * 4 + n) * 64) + l) * 4] = acc[m][n];
    }
    __syncthreads();
    if (q != 0) return;

    #pragma unroll
    for (int s = 0; s < 3; ++s) {
        const int base = (s * 2 + tl) * 4096;
        #pragma unroll
        for (int m = 0; m < 4; ++m)
            #pragma unroll
            for (int n = 0; n < 4; ++n)
                acc[m][n] += *(const f32x4*)&red[base + (((m * 4 + n) * 64) + l) * 4];
    }

    // Epilogue: leaky + dot-W2, reduce over the 64 cols of this block.
    // C/D map: col = n*16 + (lane&15), row = tl*64 + m*16 + (lane>>4)*4 + j.
    float bz[4], w2v[4];
    #pragma unroll
    for (int n = 0; n < 4; ++n) {
        const int col = ccol0 + n * 16 + lr;
        bz[n] = b1p[col];
        w2v[n] = W2p[col];
    }
    const int orow0 = brow + tl * 64 + hi * 4;
    #pragma unroll
    for (int m = 0; m < 4; ++m) {
        #pragma unroll
        for (int j = 0; j < 4; ++j) {
            float p = 0.f;
            #pragma unroll
            for (int n = 0; n < 4; ++n) {
                float z = acc[m][n][j] + bz[n];
                z = (z > 0.f) ? z : 0.01f * z;
                p = fmaf(z, w2v[n], p);
            }
            p += __shfl_xor(p, 1, 64);
            p += __shfl_xor(p, 2, 64);
            p += __shfl_xor(p, 4, 64);
            p += __shfl_xor(p, 8, 64);
            if (lr == 0)
                part[(size_t)cb * 2048 + orow0 + m * 16 + j] = p;
        }
    }
}

// ---------------------------------------------------------------------------
// prep_a: blocks 0..95 = Wd/Wc transposes; rest = casts, pads, Gram G.
// ---------------------------------------------------------------------------
#define N_DX (2048*512)
#define N_CX (2048*256)
#define PREP_A_ELEMS (N_DX + N_CX + 1024 + 1024 + 1017)

__global__ __launch_bounds__(256) void prep_a(
    const float* __restrict__ dx, const float* __restrict__ cx,
    const float* __restrict__ v,  const float* __restrict__ b1,
    const float* __restrict__ W2,
    const float* __restrict__ Wd, const float* __restrict__ Wc,
    unsigned short* __restrict__ dxb, unsigned short* __restrict__ cxb,
    float* __restrict__ b1p, float* __restrict__ W2p, float* __restrict__ G,
    unsigned short* __restrict__ WdT, unsigned short* __restrict__ WcT)
{
    __shared__ float tile[64][65];
    if (blockIdx.x < 96) {
        int bid = blockIdx.x;
        const float* in; unsigned short* out;
        int ldin, Kout, kt, nt;
        if (bid < 64) { in = Wd; out = WdT; ldin = 512; Kout = 512; kt = bid & 7; nt = bid >> 3; }
        else { bid -= 64; in = Wc; out = WcT; ldin = 512; Kout = 256; kt = bid & 3; nt = bid >> 2; }
        const int k0 = kt * 64, n0 = nt * 64;
        const int tt = threadIdx.x;
        const int nl = tt & 63, kq = tt >> 6;
        #pragma unroll
        for (int i = 0; i < 16; ++i)
            tile[kq + i * 4][nl] = in[(size_t)(k0 + kq + i * 4) * ldin + n0 + nl];
        __syncthreads();
        const int kl2 = tt & 63, nq = tt >> 6;
        #pragma unroll
        for (int i = 0; i < 16; ++i)
            out[(size_t)(n0 + nq + i * 4) * Kout + k0 + kl2] = f2bf(tile[kl2][nq + i * 4]);
        return;
    }
    int j = (blockIdx.x - 96) * 256 + threadIdx.x;
    if (j < N_DX) { dxb[j] = f2bf(dx[j]); return; }
    j -= N_DX;
    if (j < N_CX) { cxb[j] = f2bf(cx[j]); return; }
    j -= N_CX;
    if (j < 1024) { b1p[j] = (j < 1020) ? b1[j] : 0.f; return; }
    j -= 1024;
    if (j < 1024) { W2p[j] = (j < 1020) ? W2[j] : 0.f; return; }
    j -= 1024;
    if (j >= 1017) return;
    // Gram matrix for channel j: G[j][p] = sum_e v[j][f][e]*v[j][g][e], f<g
    const float* vp = v + (size_t)j * 128;
    float gacc[28];
    #pragma unroll
    for (int p = 0; p < 28; ++p) gacc[p] = 0.f;
    for (int e = 0; e < 16; ++e) {
        float vf[8];
        #pragma unroll
        for (int f = 0; f < 8; ++f) vf[f] = vp[f * 16 + e];
        int p = 0;
        #pragma unroll
        for (int f = 0; f < 8; ++f)
            #pragma unroll
            for (int g = f + 1; g < 8; ++g) { gacc[p] = fmaf(vf[f], vf[g], gacc[p]); ++p; }
    }
    #pragma unroll
    for (int p = 0; p < 28; ++p) G[(size_t)j * 32 + p] = gacc[p];
    #pragma unroll
    for (int p = 28; p < 32; ++p) G[(size_t)j * 32 + p] = 0.f;
}

// ---------------------------------------------------------------------------
// fm_w1t: blocks 0..511 = FM (Gram form); 512..1023 = W1 transpose.
// ---------------------------------------------------------------------------
__global__ __launch_bounds__(256) void fm_w1t(
    const float* __restrict__ G,
    const float* __restrict__ lin_w, const float* __restrict__ lin_b,
    unsigned short* __restrict__ resb,
    const float* __restrict__ W1, unsigned short* __restrict__ W1T)
{
    if (blockIdx.x >= 512) {
        __shared__ float tile[64][65];
        const int bid = blockIdx.x - 512;
        const int kt = bid & 31, nt = bid >> 5;
        const int k0 = kt * 64, n0 = nt * 64;
        const int tt = threadIdx.x;
        const int nl = tt & 63, kq = tt >> 6;
        #pragma unroll
        for (int i = 0; i < 16; ++i) {
            const int kl = kq + i * 4;
            const int gk = k0 + kl, gn = n0 + nl;
            tile[kl][nl] = (gk < 2041 && gn < 1020) ? W1[(size_t)gk * 1020 + gn] : 0.f;
        }
        __syncthreads();
        const int kl2 = tt & 63, nq = tt >> 6;
        #pragma unroll
        for (int i = 0; i < 16; ++i) {
            const int nl2 = nq + i * 4;
            W1T[(size_t)(n0 + nl2) * 2048 + k0 + kl2] = f2bf(tile[kl2][nl2]);
        }
        return;
    }

    __shared__ float xs[4][1032];
    const int r0 = blockIdx.x * 4;
    const int t  = threadIdx.x;

    #pragma unroll
    for (int r = 0; r < 4; ++r) {
        const ushort4 u = reinterpret_cast<const ushort4*>(resb + (size_t)(r0 + r) * 2048)[t];
        xs[r][t*4+0] = bf2f(u.x); xs[r][t*4+1] = bf2f(u.y);
        xs[r][t*4+2] = bf2f(u.z); xs[r][t*4+3] = bf2f(u.w);
    }
    if (t < 8) {
        #pragma unroll
        for (int r = 0; r < 4; ++r) xs[r][1024 + t] = 0.f;
    }
    __syncthreads();

    float lw[8];
    #pragma unroll
    for (int f = 0; f < 8; ++f) lw[f] = lin_w[f];
    const float lb = lin_b[0];

    const int ch0 = t * 4;
    float xw[4][12];
    #pragma unroll
    for (int r = 0; r < 4; ++r) {
        const float4 a = *reinterpret_cast<const float4*>(&xs[r][ch0]);
        const float4 b = *reinterpret_cast<const float4*>(&xs[r][ch0 + 4]);
        const float4 c = *reinterpret_cast<const float4*>(&xs[r][ch0 + 8]);
        xw[r][0]=a.x; xw[r][1]=a.y; xw[r][2]=a.z; xw[r][3]=a.w;
        xw[r][4]=b.x; xw[r][5]=b.y; xw[r][6]=b.z; xw[r][7]=b.w;
        xw[r][8]=c.x; xw[r][9]=c.y; xw[r][10]=c.z; xw[r][11]=c.w;
    }

    #pragma unroll
    for (int c = 0; c < 4; ++c) {
        const int ch = ch0 + c;
        float outv[4] = {0.f, 0.f, 0.f, 0.f};
        if (ch < 1017) {
            f32x4 Gv[7];
            const float* gp = G + (size_t)ch * 32;
            #pragma unroll
            for (int i = 0; i < 7; ++i) Gv[i] = *reinterpret_cast<const f32x4*>(gp + i * 4);
            float lin[4], fmv[4] = {0.f, 0.f, 0.f, 0.f};
            #pragma unroll
            for (int r = 0; r < 4; ++r) {
                float s = lb;
                #pragma unroll
                for (int f = 0; f < 8; ++f) s = fmaf(xw[r][c+f], lw[f], s);
                lin[r] = s;
            }
            int p = 0;
            #pragma unroll
            for (int f = 0; f < 8; ++f) {
                #pragma unroll
                for (int g = f + 1; g < 8; ++g) {
                    const float gfg = Gv[p >> 2][p & 3];
                    #pragma unroll
                    for (int r = 0; r < 4; ++r)
                        fmv[r] = fmaf(xw[r][c+f] * xw[r][c+g], gfg, fmv[r]);
                    ++p;
                }
            }
            #pragma unroll
            for (int r = 0; r < 4; ++r) outv[r] = lin[r] + fmv[r];
        }
        #pragma unroll
        for (int r = 0; r < 4; ++r)
            resb[(size_t)(r0 + r) * 2048 + 1024 + ch] = f2bf(outv[r]);
    }
}

// Final: out[b] = sigmoid(sum_{i<16} part[i][b] + b2)
__global__ __launch_bounds__(64) void final2_kernel(
    const float* __restrict__ part, const float* __restrict__ b2,
    float* __restrict__ out)
{
    const int b = blockIdx.x * 64 + threadIdx.x;
    float s = b2[0];
    #pragma unroll
    for (int i = 0; i < 16; ++i) s += part[(size_t)i * 2048 + b];
    out[b] = 1.f / (1.f + expf(-s));
}

extern "C" void kernel_launch(void* const* d_in, const int* in_sizes, int n_in,
                              void* d_out, int out_size, void* d_ws, size_t ws_size,
                              hipStream_t stream)
{
    const float* dx = (const float*)d_in[0];
    const float* cx = (const float*)d_in[1];
    const float* Wd = (const float*)d_in[2];
    const float* bd = (const float*)d_in[3];
    const float* Wc = (const float*)d_in[4];
    const float* bc = (const float*)d_in[5];
    const float* v  = (const float*)d_in[6];
    const float* lw = (const float*)d_in[7];
    const float* lb = (const float*)d_in[8];
    const float* W1 = (const float*)d_in[9];
    const float* b1 = (const float*)d_in[10];
    const float* W2 = (const float*)d_in[11];
    const float* b2 = (const float*)d_in[12];
    float* out = (float*)d_out;

    char* ws = (char*)d_ws;
    unsigned short* resb = (unsigned short*)(ws);                              // 8 MB
    float*          part = (float*)(ws + (8u << 20));                          // 128 KB
    unsigned short* dxb  = (unsigned short*)(ws + (9u << 20));                 // 2 MB
    unsigned short* cxb  = (unsigned short*)(ws + (11u << 20));                // 1 MB
    unsigned short* WdT  = (unsigned short*)(ws + (12u << 20));                // 512 KB
    unsigned short* WcT  = (unsigned short*)(ws + (12u << 20) + (512u << 10)); // 256 KB
    unsigned short* W1T  = (unsigned short*)(ws + (13u << 20));                // 4 MB
    float*          G    = (float*)(ws + (17u << 20));                         // 132 KB
    float*          b1p  = (float*)(ws + (17u << 20) + (192u << 10));          // 4 KB
    float*          W2p  = (float*)(ws + (17u << 20) + (196u << 10));          // 4 KB

    const int prep_a_blocks = 96 + (PREP_A_ELEMS + 255) / 256;
    hipLaunchKernelGGL(prep_a, dim3(prep_a_blocks), dim3(256), 0, stream,
                       dx, cx, v, b1, W2, Wd, Wc,
                       dxb, cxb, b1p, W2p, G, WdT, WcT);
    hipLaunchKernelGGL(gemm_top_mfma, dim3(256), dim3(512), 0, stream,
                       dxb, cxb, WdT, WcT, bd, bc, resb);
    hipLaunchKernelGGL(fm_w1t, dim3(1024), dim3(256), 0, stream,
                       G, lw, lb, resb, W1, W1T);
    hipLaunchKernelGGL(gemm_w1_mfma, dim3(256), dim3(512), 0, stream,
                       resb, W1T, b1p, W2p, part);
    hipLaunchKernelGGL(final2_kernel, dim3(32), dim3(64), 0, stream,
                       part, b2, out);
}

// Round 10
// 56.692 us; speedup vs baseline: 1.2610x; 1.0780x over previous
//
#include <hip/hip_runtime.h>
#include <math.h>

// NDF=512 NCF=256 NCC=256 EMB=16 FIELD=8 B=2048
// NH0=1024 CHANNEL=1017 HID=1020 K3=2041
// resb: [2048][2048] bf16 (cols 0..1023 = x, 1024..2040 = x_fm2, 2041..2047 = 0)

typedef __bf16 bf16x8 __attribute__((ext_vector_type(8)));
typedef float  f32x4  __attribute__((ext_vector_type(4)));

__device__ __forceinline__ unsigned short f2bf(float x) {
    union { float f; unsigned u; } c; c.f = x;
    unsigned r = c.u + 0x7fffu + ((c.u >> 16) & 1u);
    return (unsigned short)(r >> 16);
}
__device__ __forceinline__ float bf2f(unsigned short u) {
    union { unsigned u; float f; } c; c.u = ((unsigned)u) << 16;
    return c.f;
}

#define GLDS(g, l) __builtin_amdgcn_global_load_lds( \
    (const __attribute__((address_space(1))) void*)(g), \
    (__attribute__((address_space(3))) void*)(l), 16, 0, 0)

// ---------------------------------------------------------------------------
// GEMM body A (for gemm_top): BM=128 BN=64 Kstep=128, 8 waves,
// 2-way K-split (quads), wave tile 64x32, 3-buffer vmcnt(6). (round-8 proven)
// ---------------------------------------------------------------------------
__device__ __forceinline__ void gemm_body_top(
    const unsigned short* __restrict__ A, int lda,
    const unsigned short* __restrict__ B, int ldb,
    const float* __restrict__ bias,
    unsigned short* __restrict__ Cb, int ldc,
    int ccol0, int brow, int nbase, int K)
{
    __shared__ __align__(128) unsigned short As[3][128 * 128];
    __shared__ __align__(128) unsigned short Bs[3][64 * 128];

    const int t = threadIdx.x;
    const int w = t >> 6;
    const int l = t & 63;
    const int lr = l & 15, hi = l >> 4;
    const int lrx = (lr & 7) << 3;
    const int q   = w >> 2;
    const int sub = w & 3;
    const int wr = sub >> 1, wc = sub & 1;
    const int kq = q << 6;

    f32x4 acc[4][2];
    #pragma unroll
    for (int m = 0; m < 4; ++m)
        #pragma unroll
        for (int n = 0; n < 2; ++n) acc[m][n] = f32x4{0.f, 0.f, 0.f, 0.f};

    const int nk = K >> 7;

    auto STAGE = [&](int buf, int k0) {
        #pragma unroll
        for (int i = 0; i < 4; ++i) {
            const int r0 = w * 16 + i * 4;
            const int row = r0 + (l >> 4);
            const int se = ((l & 15) ^ (row & 7)) << 3;
            GLDS(A + (size_t)(brow + row) * lda + k0 + se, &As[buf][r0 * 128]);
        }
        #pragma unroll
        for (int i = 0; i < 2; ++i) {
            const int r0 = w * 8 + i * 4;
            const int row = r0 + (l >> 4);
            const int se = ((l & 15) ^ (row & 7)) << 3;
            GLDS(B + (size_t)(nbase + row) * ldb + k0 + se, &Bs[buf][r0 * 128]);
        }
    };

    STAGE(0, 0);
    if (nk > 1) STAGE(1, 128);

    for (int tt = 0; tt < nk; ++tt) {
        if (tt + 1 < nk) asm volatile("s_waitcnt vmcnt(6)" ::: "memory");
        else             asm volatile("s_waitcnt vmcnt(0)" ::: "memory");
        __builtin_amdgcn_s_barrier();
        if (tt + 2 < nk) STAGE((tt + 2) % 3, (tt + 2) << 7);

        const unsigned short* pa = &As[tt % 3][0];
        const unsigned short* pb = &Bs[tt % 3][0];
        bf16x8 af[4][2], bfv[2][2];
        #pragma unroll
        for (int m = 0; m < 4; ++m) {
            const int row = wr * 64 + m * 16 + lr;
            #pragma unroll
            for (int ks = 0; ks < 2; ++ks)
                af[m][ks] = *(const bf16x8*)&pa[row * 128 + ((kq + ks * 32 + hi * 8) ^ lrx)];
        }
        #pragma unroll
        for (int n = 0; n < 2; ++n) {
            const int row = wc * 32 + n * 16 + lr;
            #pragma unroll
            for (int ks = 0; ks < 2; ++ks)
                bfv[n][ks] = *(const bf16x8*)&pb[row * 128 + ((kq + ks * 32 + hi * 8) ^ lrx)];
        }
        #pragma unroll
        for (int ks = 0; ks < 2; ++ks)
            #pragma unroll
            for (int m = 0; m < 4; ++m)
                #pragma unroll
                for (int n = 0; n < 2; ++n)
                    acc[m][n] = __builtin_amdgcn_mfma_f32_16x16x32_bf16(af[m][ks], bfv[n][ks], acc[m][n], 0, 0, 0);
    }

    __syncthreads();
    float* red = (float*)&As[0][0];
    if (q == 1) {
        #pragma unroll
        for (int m = 0; m < 4; ++m)
            #pragma unroll
            for (int n = 0; n < 2; ++n)
                *(f32x4*)&red[(((sub * 8) + m * 2 + n) * 64 + l) * 4] = acc[m][n];
    }
    __syncthreads();
    if (q != 0) return;

    #pragma unroll
    for (int m = 0; m < 4; ++m)
        #pragma unroll
        for (int n = 0; n < 2; ++n)
            acc[m][n] += *(const f32x4*)&red[(((sub * 8) + m * 2 + n) * 64 + l) * 4];

    const int orow0 = brow + wr * 64 + hi * 4;
    #pragma unroll
    for (int m = 0; m < 4; ++m) {
        #pragma unroll
        for (int n = 0; n < 2; ++n) {
            const int col = ccol0 + wc * 32 + n * 16 + lr;
            const float bz = bias[col];
            #pragma unroll
            for (int j = 0; j < 4; ++j) {
                float z = acc[m][n][j] + bz;
                z = fmaxf(z, 0.f);
                Cb[(size_t)(orow0 + m * 16 + j) * ldc + col] = f2bf(z);
            }
        }
    }
}

__global__ __launch_bounds__(512) void gemm_top_mfma(
    const unsigned short* __restrict__ dxb, const unsigned short* __restrict__ cxb,
    const unsigned short* __restrict__ WdT, const unsigned short* __restrict__ WcT,
    const float* __restrict__ bd, const float* __restrict__ bc,
    unsigned short* __restrict__ resb)
{
    const int bid = blockIdx.x;                   // 256 blocks
    const int swz = (bid & 7) * 32 + (bid >> 3);  // bijective XCD swizzle
    const int cb = swz & 15;
    const int brow = (swz >> 4) * 128;
    const int ccol0 = cb * 64;
    if (cb < 8)
        gemm_body_top(dxb, 512, WdT, 512, bd, resb, 2048, ccol0, brow, ccol0, 512);
    else
        gemm_body_top(cxb, 256, WcT, 256, bc - 512, resb, 2048, ccol0, brow, ccol0 - 512, 256);
}

// ---------------------------------------------------------------------------
// GEMM body B (gemm_w1): BM=128 BN=64 Kstep=128, 8 waves = 2 m-tiles x 4-way
// K-split, wave tile 64x64 (acc[4][4]) -> 8 ds_read per 16 MFMA.
// 3-buffer vmcnt(6). 4-way cross-quad LDS reduction, fused leaky+dot-W2
// epilogue -> part[16][2048].
// ---------------------------------------------------------------------------
__global__ __launch_bounds__(512) void gemm_w1_mfma(
    const unsigned short* __restrict__ Ab, const unsigned short* __restrict__ Bb,
    const float* __restrict__ b1p, const float* __restrict__ W2p,
    float* __restrict__ part)
{
    __shared__ __align__(128) unsigned short As[3][128 * 128];  // 96 KB
    __shared__ __align__(128) unsigned short Bs[3][64 * 128];   // 48 KB

    const int bid = blockIdx.x;
    const int swz = (bid & 7) * 32 + (bid >> 3);
    const int cb = swz & 15;
    const int brow = (swz >> 4) * 128;
    const int nbase = cb * 64;
    const int ccol0 = cb * 64;
    const int lda = 2048, ldb = 2048;
    const int K = 2048;

    const int t = threadIdx.x;
    const int w = t >> 6;
    const int l = t & 63;
    const int lr = l & 15, hi = l >> 4;
    const int lrx = (lr & 7) << 3;
    const int tl = w & 1;           // m-tile (rows tl*64)
    const int q  = w >> 1;          // k-quad (k-cols [32q, 32q+32) of the step)
    const int kq = q << 5;

    f32x4 acc[4][4];
    #pragma unroll
    for (int m = 0; m < 4; ++m)
        #pragma unroll
        for (int n = 0; n < 4; ++n) acc[m][n] = f32x4{0.f, 0.f, 0.f, 0.f};

    const int nk = K >> 7;          // 16

    auto STAGE = [&](int buf, int k0) {
        #pragma unroll
        for (int i = 0; i < 4; ++i) {
            const int r0 = w * 16 + i * 4;
            const int row = r0 + (l >> 4);
            const int se = ((l & 15) ^ (row & 7)) << 3;
            GLDS(Ab + (size_t)(brow + row) * lda + k0 + se, &As[buf][r0 * 128]);
        }
        #pragma unroll
        for (int i = 0; i < 2; ++i) {
            const int r0 = w * 8 + i * 4;
            const int row = r0 + (l >> 4);
            const int se = ((l & 15) ^ (row & 7)) << 3;
            GLDS(Bb + (size_t)(nbase + row) * ldb + k0 + se, &Bs[buf][r0 * 128]);
        }
    };

    STAGE(0, 0);
    STAGE(1, 128);

    for (int tt = 0; tt < nk; ++tt) {
        if (tt + 1 < nk) asm volatile("s_waitcnt vmcnt(6)" ::: "memory");
        else             asm volatile("s_waitcnt vmcnt(0)" ::: "memory");
        __builtin_amdgcn_s_barrier();
        if (tt + 2 < nk) STAGE((tt + 2) % 3, (tt + 2) << 7);

        const unsigned short* pa = &As[tt % 3][0];
        const unsigned short* pb = &Bs[tt % 3][0];
        bf16x8 af[4], bfv[4];
        #pragma unroll
        for (int m = 0; m < 4; ++m) {
            const int row = tl * 64 + m * 16 + lr;
            af[m] = *(const bf16x8*)&pa[row * 128 + ((kq + hi * 8) ^ lrx)];
        }
        #pragma unroll
        for (int n = 0; n < 4; ++n) {
            const int row = n * 16 + lr;
            bfv[n] = *(const bf16x8*)&pb[row * 128 + ((kq + hi * 8) ^ lrx)];
        }
        #pragma unroll
        for (int m = 0; m < 4; ++m)
            #pragma unroll
            for (int n = 0; n < 4; ++n)
                acc[m][n] = __builtin_amdgcn_mfma_f32_16x16x32_bf16(af[m], bfv[n], acc[m][n], 0, 0, 0);
    }

    // Cross-quad reduction: quads 1..3 write 64 f32/lane; quad 0 accumulates.
    __syncthreads();
    float* red = (float*)&As[0][0];   // 96 KB needed, 96 KB available
    if (q != 0) {
        const int base = ((q - 1) * 2 + tl) * 4096;
        #pragma unroll
        for (int m = 0; m < 4; ++m)
            #pragma unroll
            for (int n = 0; n < 4; ++n)
                *(f32x4*)&red[base + (((m * 4 + n) * 64) + l) * 4] = acc[m][n];
    }
    __syncthreads();
    if (q != 0) return;

    #pragma unroll
    for (int s = 0; s < 3; ++s) {
        const int base = (s * 2 + tl) * 4096;
        #pragma unroll
        for (int m = 0; m < 4; ++m)
            #pragma unroll
            for (int n = 0; n < 4; ++n)
                acc[m][n] += *(const f32x4*)&red[base + (((m * 4 + n) * 64) + l) * 4];
    }

    // Epilogue: leaky + dot-W2, reduce over the 64 cols of this block.
    float bz[4], w2v[4];
    #pragma unroll
    for (int n = 0; n < 4; ++n) {
        const int col = ccol0 + n * 16 + lr;
        bz[n] = b1p[col];
        w2v[n] = W2p[col];
    }
    const int orow0 = brow + tl * 64 + hi * 4;
    #pragma unroll
    for (int m = 0; m < 4; ++m) {
        #pragma unroll
        for (int j = 0; j < 4; ++j) {
            float p = 0.f;
            #pragma unroll
            for (int n = 0; n < 4; ++n) {
                float z = acc[m][n][j] + bz[n];
                z = (z > 0.f) ? z : 0.01f * z;
                p = fmaf(z, w2v[n], p);
            }
            p += __shfl_xor(p, 1, 64);
            p += __shfl_xor(p, 2, 64);
            p += __shfl_xor(p, 4, 64);
            p += __shfl_xor(p, 8, 64);
            if (lr == 0)
                part[(size_t)cb * 2048 + orow0 + m * 16 + j] = p;
        }
    }
}

// ---------------------------------------------------------------------------
// prep_a: blocks 0..95 = Wd/Wc transposes; rest = VECTORIZED casts, pads, G.
// dx: 262144 float4 -> ushort4; cx: 131072 float4 -> ushort4.
// ---------------------------------------------------------------------------
#define N_DX4 262144
#define N_CX4 131072
#define PREP_A_ELEMS (N_DX4 + N_CX4 + 1024 + 1024 + 1017)

__global__ __launch_bounds__(256) void prep_a(
    const float* __restrict__ dx, const float* __restrict__ cx,
    const float* __restrict__ v,  const float* __restrict__ b1,
    const float* __restrict__ W2,
    const float* __restrict__ Wd, const float* __restrict__ Wc,
    unsigned short* __restrict__ dxb, unsigned short* __restrict__ cxb,
    float* __restrict__ b1p, float* __restrict__ W2p, float* __restrict__ G,
    unsigned short* __restrict__ WdT, unsigned short* __restrict__ WcT)
{
    __shared__ float tile[64][65];
    if (blockIdx.x < 96) {
        int bid = blockIdx.x;
        const float* in; unsigned short* out;
        int ldin, Kout, kt, nt;
        if (bid < 64) { in = Wd; out = WdT; ldin = 512; Kout = 512; kt = bid & 7; nt = bid >> 3; }
        else { bid -= 64; in = Wc; out = WcT; ldin = 512; Kout = 256; kt = bid & 3; nt = bid >> 2; }
        const int k0 = kt * 64, n0 = nt * 64;
        const int tt = threadIdx.x;
        const int nl = tt & 63, kq = tt >> 6;
        #pragma unroll
        for (int i = 0; i < 16; ++i)
            tile[kq + i * 4][nl] = in[(size_t)(k0 + kq + i * 4) * ldin + n0 + nl];
        __syncthreads();
        const int kl2 = tt & 63, nq = tt >> 6;
        #pragma unroll
        for (int i = 0; i < 16; ++i)
            out[(size_t)(n0 + nq + i * 4) * Kout + k0 + kl2] = f2bf(tile[kl2][nq + i * 4]);
        return;
    }
    int j = (blockIdx.x - 96) * 256 + threadIdx.x;
    if (j < N_DX4) {
        const float4 vv = reinterpret_cast<const float4*>(dx)[j];
        ushort4 o;
        o.x = f2bf(vv.x); o.y = f2bf(vv.y); o.z = f2bf(vv.z); o.w = f2bf(vv.w);
        reinterpret_cast<ushort4*>(dxb)[j] = o;
        return;
    }
    j -= N_DX4;
    if (j < N_CX4) {
        const float4 vv = reinterpret_cast<const float4*>(cx)[j];
        ushort4 o;
        o.x = f2bf(vv.x); o.y = f2bf(vv.y); o.z = f2bf(vv.z); o.w = f2bf(vv.w);
        reinterpret_cast<ushort4*>(cxb)[j] = o;
        return;
    }
    j -= N_CX4;
    if (j < 1024) { b1p[j] = (j < 1020) ? b1[j] : 0.f; return; }
    j -= 1024;
    if (j < 1024) { W2p[j] = (j < 1020) ? W2[j] : 0.f; return; }
    j -= 1024;
    if (j >= 1017) return;
    // Gram matrix for channel j: G[j][p] = sum_e v[j][f][e]*v[j][g][e], f<g
    const float* vp = v + (size_t)j * 128;
    float gacc[28];
    #pragma unroll
    for (int p = 0; p < 28; ++p) gacc[p] = 0.f;
    for (int e = 0; e < 16; ++e) {
        float vf[8];
        #pragma unroll
        for (int f = 0; f < 8; ++f) vf[f] = vp[f * 16 + e];
        int p = 0;
        #pragma unroll
        for (int f = 0; f < 8; ++f)
            #pragma unroll
            for (int g = f + 1; g < 8; ++g) { gacc[p] = fmaf(vf[f], vf[g], gacc[p]); ++p; }
    }
    #pragma unroll
    for (int p = 0; p < 28; ++p) G[(size_t)j * 32 + p] = gacc[p];
    #pragma unroll
    for (int p = 28; p < 32; ++p) G[(size_t)j * 32 + p] = 0.f;
}

// ---------------------------------------------------------------------------
// fm_w1t: blocks 0..511 = FM (Gram form); 512..1023 = W1 transpose.
// ---------------------------------------------------------------------------
__global__ __launch_bounds__(256) void fm_w1t(
    const float* __restrict__ G,
    const float* __restrict__ lin_w, const float* __restrict__ lin_b,
    unsigned short* __restrict__ resb,
    const float* __restrict__ W1, unsigned short* __restrict__ W1T)
{
    if (blockIdx.x >= 512) {
        __shared__ float tile[64][65];
        const int bid = blockIdx.x - 512;
        const int kt = bid & 31, nt = bid >> 5;
        const int k0 = kt * 64, n0 = nt * 64;
        const int tt = threadIdx.x;
        const int nl = tt & 63, kq = tt >> 6;
        #pragma unroll
        for (int i = 0; i < 16; ++i) {
            const int kl = kq + i * 4;
            const int gk = k0 + kl, gn = n0 + nl;
            tile[kl][nl] = (gk < 2041 && gn < 1020) ? W1[(size_t)gk * 1020 + gn] : 0.f;
        }
        __syncthreads();
        const int kl2 = tt & 63, nq = tt >> 6;
        #pragma unroll
        for (int i = 0; i < 16; ++i) {
            const int nl2 = nq + i * 4;
            W1T[(size_t)(n0 + nl2) * 2048 + k0 + kl2] = f2bf(tile[kl2][nl2]);
        }
        return;
    }

    __shared__ float xs[4][1032];
    const int r0 = blockIdx.x * 4;
    const int t  = threadIdx.x;

    #pragma unroll
    for (int r = 0; r < 4; ++r) {
        const ushort4 u = reinterpret_cast<const ushort4*>(resb + (size_t)(r0 + r) * 2048)[t];
        xs[r][t*4+0] = bf2f(u.x); xs[r][t*4+1] = bf2f(u.y);
        xs[r][t*4+2] = bf2f(u.z); xs[r][t*4+3] = bf2f(u.w);
    }
    if (t < 8) {
        #pragma unroll
        for (int r = 0; r < 4; ++r) xs[r][1024 + t] = 0.f;
    }
    __syncthreads();

    float lw[8];
    #pragma unroll
    for (int f = 0; f < 8; ++f) lw[f] = lin_w[f];
    const float lb = lin_b[0];

    const int ch0 = t * 4;
    float xw[4][12];
    #pragma unroll
    for (int r = 0; r < 4; ++r) {
        const float4 a = *reinterpret_cast<const float4*>(&xs[r][ch0]);
        const float4 b = *reinterpret_cast<const float4*>(&xs[r][ch0 + 4]);
        const float4 c = *reinterpret_cast<const float4*>(&xs[r][ch0 + 8]);
        xw[r][0]=a.x; xw[r][1]=a.y; xw[r][2]=a.z; xw[r][3]=a.w;
        xw[r][4]=b.x; xw[r][5]=b.y; xw[r][6]=b.z; xw[r][7]=b.w;
        xw[r][8]=c.x; xw[r][9]=c.y; xw[r][10]=c.z; xw[r][11]=c.w;
    }

    #pragma unroll
    for (int c = 0; c < 4; ++c) {
        const int ch = ch0 + c;
        float outv[4] = {0.f, 0.f, 0.f, 0.f};
        if (ch < 1017) {
            f32x4 Gv[7];
            const float* gp = G + (size_t)ch * 32;
            #pragma unroll
            for (int i = 0; i < 7; ++i) Gv[i] = *reinterpret_cast<const f32x4*>(gp + i * 4);
            float lin[4], fmv[4] = {0.f, 0.f, 0.f, 0.f};
            #pragma unroll
            for (int r = 0; r < 4; ++r) {
                float s = lb;
                #pragma unroll
                for (int f = 0; f < 8; ++f) s = fmaf(xw[r][c+f], lw[f], s);
                lin[r] = s;
            }
            int p = 0;
            #pragma unroll
            for (int f = 0; f < 8; ++f) {
                #pragma unroll
                for (int g = f + 1; g < 8; ++g) {
                    const float gfg = Gv[p >> 2][p & 3];
                    #pragma unroll
                    for (int r = 0; r < 4; ++r)
                        fmv[r] = fmaf(xw[r][c+f] * xw[r][c+g], gfg, fmv[r]);
                    ++p;
                }
            }
            #pragma unroll
            for (int r = 0; r < 4; ++r) outv[r] = lin[r] + fmv[r];
        }
        #pragma unroll
        for (int r = 0; r < 4; ++r)
            resb[(size_t)(r0 + r) * 2048 + 1024 + ch] = f2bf(outv[r]);
    }
}

// Final: out[b] = sigmoid(sum_{i<16} part[i][b] + b2)
__global__ __launch_bounds__(64) void final2_kernel(
    const float* __restrict__ part, const float* __restrict__ b2,
    float* __restrict__ out)
{
    const int b = blockIdx.x * 64 + threadIdx.x;
    float s = b2[0];
    #pragma unroll
    for (int i = 0; i < 16; ++i) s += part[(size_t)i * 2048 + b];
    out[b] = 1.f / (1.f + expf(-s));
}

extern "C" void kernel_launch(void* const* d_in, const int* in_sizes, int n_in,
                              void* d_out, int out_size, void* d_ws, size_t ws_size,
                              hipStream_t stream)
{
    const float* dx = (const float*)d_in[0];
    const float* cx = (const float*)d_in[1];
    const float* Wd = (const float*)d_in[2];
    const float* bd = (const float*)d_in[3];
    const float* Wc = (const float*)d_in[4];
    const float* bc = (const float*)d_in[5];
    const float* v  = (const float*)d_in[6];
    const float* lw = (const float*)d_in[7];
    const float* lb = (const float*)d_in[8];
    const float* W1 = (const float*)d_in[9];
    const float* b1 = (const float*)d_in[10];
    const float* W2 = (const float*)d_in[11];
    const float* b2 = (const float*)d_in[12];
    float* out = (float*)d_out;

    char* ws = (char*)d_ws;
    unsigned short* resb = (unsigned short*)(ws);                              // 8 MB
    float*          part = (float*)(ws + (8u << 20));                          // 128 KB
    unsigned short* dxb  = (unsigned short*)(ws + (9u << 20));                 // 2 MB
    unsigned short* cxb  = (unsigned short*)(ws + (11u << 20));                // 1 MB
    unsigned short* WdT  = (unsigned short*)(ws + (12u << 20));                // 512 KB
    unsigned short* WcT  = (unsigned short*)(ws + (12u << 20) + (512u << 10)); // 256 KB
    unsigned short* W1T  = (unsigned short*)(ws + (13u << 20));                // 4 MB
    float*          G    = (float*)(ws + (17u << 20));                         // 132 KB
    float*          b1p  = (float*)(ws + (17u << 20) + (192u << 10));          // 4 KB
    float*          W2p  = (float*)(ws + (17u << 20) + (196u << 10));          // 4 KB

    const int prep_a_blocks = 96 + (PREP_A_ELEMS + 255) / 256;
    hipLaunchKernelGGL(prep_a, dim3(prep_a_blocks), dim3(256), 0, stream,
                       dx, cx, v, b1, W2, Wd, Wc,
                       dxb, cxb, b1p, W2p, G, WdT, WcT);
    hipLaunchKernelGGL(gemm_top_mfma, dim3(256), dim3(512), 0, stream,
                       dxb, cxb, WdT, WcT, bd, bc, resb);
    hipLaunchKernelGGL(fm_w1t, dim3(1024), dim3(256), 0, stream,
                       G, lw, lb, resb, W1, W1T);
    hipLaunchKernelGGL(gemm_w1_mfma, dim3(256), dim3(512), 0, stream,
                       resb, W1T, b1p, W2p, part);
    hipLaunchKernelGGL(final2_kernel, dim3(32), dim3(64), 0, stream,
                       part, b2, out);
}

// Round 11
// 53.421 us; speedup vs baseline: 1.3382x; 1.0612x over previous
//
#include <hip/hip_runtime.h>
#include <math.h>

// NDF=512 NCF=256 NCC=256 EMB=16 FIELD=8 B=2048
// NH0=1024 CHANNEL=1017 HID=1020 K3=2041
// resb: [2048][2048] bf16 (cols 0..1023 = x, 1024..2040 = x_fm2, 2041..2047 = 0)

typedef __bf16 bf16x8 __attribute__((ext_vector_type(8)));
typedef float  f32x4  __attribute__((ext_vector_type(4)));

__device__ __forceinline__ unsigned short f2bf(float x) {
    union { float f; unsigned u; } c; c.f = x;
    unsigned r = c.u + 0x7fffu + ((c.u >> 16) & 1u);
    return (unsigned short)(r >> 16);
}
__device__ __forceinline__ float bf2f(unsigned short u) {
    union { unsigned u; float f; } c; c.u = ((unsigned)u) << 16;
    return c.f;
}

#define GLDS(g, l) __builtin_amdgcn_global_load_lds( \
    (const __attribute__((address_space(1))) void*)(g), \
    (__attribute__((address_space(3))) void*)(l), 16, 0, 0)

// ---------------------------------------------------------------------------
// GEMM body A (for gemm_top): BM=128 BN=64 Kstep=128, 8 waves,
// 2-way K-split (quads), wave tile 64x32, 3-buffer vmcnt(6). (round-8 proven)
// ---------------------------------------------------------------------------
__device__ __forceinline__ void gemm_body_top(
    const unsigned short* __restrict__ A, int lda,
    const unsigned short* __restrict__ B, int ldb,
    const float* __restrict__ bias,
    unsigned short* __restrict__ Cb, int ldc,
    int ccol0, int brow, int nbase, int K)
{
    __shared__ __align__(128) unsigned short As[3][128 * 128];
    __shared__ __align__(128) unsigned short Bs[3][64 * 128];

    const int t = threadIdx.x;
    const int w = t >> 6;
    const int l = t & 63;
    const int lr = l & 15, hi = l >> 4;
    const int lrx = (lr & 7) << 3;
    const int q   = w >> 2;
    const int sub = w & 3;
    const int wr = sub >> 1, wc = sub & 1;
    const int kq = q << 6;

    f32x4 acc[4][2];
    #pragma unroll
    for (int m = 0; m < 4; ++m)
        #pragma unroll
        for (int n = 0; n < 2; ++n) acc[m][n] = f32x4{0.f, 0.f, 0.f, 0.f};

    const int nk = K >> 7;

    auto STAGE = [&](int buf, int k0) {
        #pragma unroll
        for (int i = 0; i < 4; ++i) {
            const int r0 = w * 16 + i * 4;
            const int row = r0 + (l >> 4);
            const int se = ((l & 15) ^ (row & 7)) << 3;
            GLDS(A + (size_t)(brow + row) * lda + k0 + se, &As[buf][r0 * 128]);
        }
        #pragma unroll
        for (int i = 0; i < 2; ++i) {
            const int r0 = w * 8 + i * 4;
            const int row = r0 + (l >> 4);
            const int se = ((l & 15) ^ (row & 7)) << 3;
            GLDS(B + (size_t)(nbase + row) * ldb + k0 + se, &Bs[buf][r0 * 128]);
        }
    };

    STAGE(0, 0);
    if (nk > 1) STAGE(1, 128);

    for (int tt = 0; tt < nk; ++tt) {
        if (tt + 1 < nk) asm volatile("s_waitcnt vmcnt(6)" ::: "memory");
        else             asm volatile("s_waitcnt vmcnt(0)" ::: "memory");
        __builtin_amdgcn_s_barrier();
        if (tt + 2 < nk) STAGE((tt + 2) % 3, (tt + 2) << 7);

        const unsigned short* pa = &As[tt % 3][0];
        const unsigned short* pb = &Bs[tt % 3][0];
        bf16x8 af[4][2], bfv[2][2];
        #pragma unroll
        for (int m = 0; m < 4; ++m) {
            const int row = wr * 64 + m * 16 + lr;
            #pragma unroll
            for (int ks = 0; ks < 2; ++ks)
                af[m][ks] = *(const bf16x8*)&pa[row * 128 + ((kq + ks * 32 + hi * 8) ^ lrx)];
        }
        #pragma unroll
        for (int n = 0; n < 2; ++n) {
            const int row = wc * 32 + n * 16 + lr;
            #pragma unroll
            for (int ks = 0; ks < 2; ++ks)
                bfv[n][ks] = *(const bf16x8*)&pb[row * 128 + ((kq + ks * 32 + hi * 8) ^ lrx)];
        }
        #pragma unroll
        for (int ks = 0; ks < 2; ++ks)
            #pragma unroll
            for (int m = 0; m < 4; ++m)
                #pragma unroll
                for (int n = 0; n < 2; ++n)
                    acc[m][n] = __builtin_amdgcn_mfma_f32_16x16x32_bf16(af[m][ks], bfv[n][ks], acc[m][n], 0, 0, 0);
    }

    __syncthreads();
    float* red = (float*)&As[0][0];
    if (q == 1) {
        #pragma unroll
        for (int m = 0; m < 4; ++m)
            #pragma unroll
            for (int n = 0; n < 2; ++n)
                *(f32x4*)&red[(((sub * 8) + m * 2 + n) * 64 + l) * 4] = acc[m][n];
    }
    __syncthreads();
    if (q != 0) return;

    #pragma unroll
    for (int m = 0; m < 4; ++m)
        #pragma unroll
        for (int n = 0; n < 2; ++n)
            acc[m][n] += *(const f32x4*)&red[(((sub * 8) + m * 2 + n) * 64 + l) * 4];

    const int orow0 = brow + wr * 64 + hi * 4;
    #pragma unroll
    for (int m = 0; m < 4; ++m) {
        #pragma unroll
        for (int n = 0; n < 2; ++n) {
            const int col = ccol0 + wc * 32 + n * 16 + lr;
            const float bz = bias[col];
            #pragma unroll
            for (int j = 0; j < 4; ++j) {
                float z = acc[m][n][j] + bz;
                z = fmaxf(z, 0.f);
                Cb[(size_t)(orow0 + m * 16 + j) * ldc + col] = f2bf(z);
            }
        }
    }
}

__global__ __launch_bounds__(512) void gemm_top_mfma(
    const unsigned short* __restrict__ dxb, const unsigned short* __restrict__ cxb,
    const unsigned short* __restrict__ WdT, const unsigned short* __restrict__ WcT,
    const float* __restrict__ bd, const float* __restrict__ bc,
    unsigned short* __restrict__ resb)
{
    const int bid = blockIdx.x;                   // 256 blocks
    const int swz = (bid & 7) * 32 + (bid >> 3);  // bijective XCD swizzle
    const int cb = swz & 15;
    const int brow = (swz >> 4) * 128;
    const int ccol0 = cb * 64;
    if (cb < 8)
        gemm_body_top(dxb, 512, WdT, 512, bd, resb, 2048, ccol0, brow, ccol0, 512);
    else
        gemm_body_top(cxb, 256, WcT, 256, bc - 512, resb, 2048, ccol0, brow, ccol0 - 512, 256);
}

// ---------------------------------------------------------------------------
// GEMM body B (gemm_w1): BM=128 BN=64 Kstep=128, 8 waves = 2 m-tiles x 4-way
// K-split, wave tile 64x64 (acc[4][4]) -> 8 ds_read per 16 MFMA.
// 3-buffer vmcnt(6). 4-way cross-quad LDS reduction, fused leaky+dot-W2
// epilogue -> part[16][2048].
// ---------------------------------------------------------------------------
__global__ __launch_bounds__(512) void gemm_w1_mfma(
    const unsigned short* __restrict__ Ab, const unsigned short* __restrict__ Bb,
    const float* __restrict__ b1p, const float* __restrict__ W2p,
    float* __restrict__ part)
{
    __shared__ __align__(128) unsigned short As[3][128 * 128];  // 96 KB
    __shared__ __align__(128) unsigned short Bs[3][64 * 128];   // 48 KB

    const int bid = blockIdx.x;
    const int swz = (bid & 7) * 32 + (bid >> 3);
    const int cb = swz & 15;
    const int brow = (swz >> 4) * 128;
    const int nbase = cb * 64;
    const int ccol0 = cb * 64;
    const int lda = 2048, ldb = 2048;
    const int K = 2048;

    const int t = threadIdx.x;
    const int w = t >> 6;
    const int l = t & 63;
    const int lr = l & 15, hi = l >> 4;
    const int lrx = (lr & 7) << 3;
    const int tl = w & 1;           // m-tile (rows tl*64)
    const int q  = w >> 1;          // k-quad (k-cols [32q, 32q+32) of the step)
    const int kq = q << 5;

    f32x4 acc[4][4];
    #pragma unroll
    for (int m = 0; m < 4; ++m)
        #pragma unroll
        for (int n = 0; n < 4; ++n) acc[m][n] = f32x4{0.f, 0.f, 0.f, 0.f};

    const int nk = K >> 7;          // 16

    auto STAGE = [&](int buf, int k0) {
        #pragma unroll
        for (int i = 0; i < 4; ++i) {
            const int r0 = w * 16 + i * 4;
            const int row = r0 + (l >> 4);
            const int se = ((l & 15) ^ (row & 7)) << 3;
            GLDS(Ab + (size_t)(brow + row) * lda + k0 + se, &As[buf][r0 * 128]);
        }
        #pragma unroll
        for (int i = 0; i < 2; ++i) {
            const int r0 = w * 8 + i * 4;
            const int row = r0 + (l >> 4);
            const int se = ((l & 15) ^ (row & 7)) << 3;
            GLDS(Bb + (size_t)(nbase + row) * ldb + k0 + se, &Bs[buf][r0 * 128]);
        }
    };

    STAGE(0, 0);
    STAGE(1, 128);

    for (int tt = 0; tt < nk; ++tt) {
        if (tt + 1 < nk) asm volatile("s_waitcnt vmcnt(6)" ::: "memory");
        else             asm volatile("s_waitcnt vmcnt(0)" ::: "memory");
        __builtin_amdgcn_s_barrier();
        if (tt + 2 < nk) STAGE((tt + 2) % 3, (tt + 2) << 7);

        const unsigned short* pa = &As[tt % 3][0];
        const unsigned short* pb = &Bs[tt % 3][0];
        bf16x8 af[4], bfv[4];
        #pragma unroll
        for (int m = 0; m < 4; ++m) {
            const int row = tl * 64 + m * 16 + lr;
            af[m] = *(const bf16x8*)&pa[row * 128 + ((kq + hi * 8) ^ lrx)];
        }
        #pragma unroll
        for (int n = 0; n < 4; ++n) {
            const int row = n * 16 + lr;
            bfv[n] = *(const bf16x8*)&pb[row * 128 + ((kq + hi * 8) ^ lrx)];
        }
        #pragma unroll
        for (int m = 0; m < 4; ++m)
            #pragma unroll
            for (int n = 0; n < 4; ++n)
                acc[m][n] = __builtin_amdgcn_mfma_f32_16x16x32_bf16(af[m], bfv[n], acc[m][n], 0, 0, 0);
    }

    // Cross-quad reduction: quads 1..3 write 64 f32/lane; quad 0 accumulates.
    __syncthreads();
    float* red = (float*)&As[0][0];   // 96 KB needed, 96 KB available
    if (q != 0) {
        const int base = ((q - 1) * 2 + tl) * 4096;
        #pragma unroll
        for (int m = 0; m < 4; ++m)
            #pragma unroll
            for (int n = 0; n < 4; ++n)
                *(f32x4*)&red[base + (((m * 4 + n) * 64) + l) * 4] = acc[m][n];
    }
    __syncthreads();
    if (q != 0) return;

    #pragma unroll
    for (int s = 0; s < 3; ++s) {
        const int base = (s * 2 + tl) * 4096;
        #pragma unroll
        for (int m = 0; m < 4; ++m)
            #pragma unroll
            for (int n = 0; n < 4; ++n)
                acc[m][n] += *(const f32x4*)&red[base + (((m * 4 + n) * 64) + l) * 4];
    }

    // Epilogue: leaky + dot-W2, reduce over the 64 cols of this block.
    float bz[4], w2v[4];
    #pragma unroll
    for (int n = 0; n < 4; ++n) {
        const int col = ccol0 + n * 16 + lr;
        bz[n] = b1p[col];
        w2v[n] = W2p[col];
    }
    const int orow0 = brow + tl * 64 + hi * 4;
    #pragma unroll
    for (int m = 0; m < 4; ++m) {
        #pragma unroll
        for (int j = 0; j < 4; ++j) {
            float p = 0.f;
            #pragma unroll
            for (int n = 0; n < 4; ++n) {
                float z = acc[m][n][j] + bz[n];
                z = (z > 0.f) ? z : 0.01f * z;
                p = fmaf(z, w2v[n], p);
            }
            p += __shfl_xor(p, 1, 64);
            p += __shfl_xor(p, 2, 64);
            p += __shfl_xor(p, 4, 64);
            p += __shfl_xor(p, 8, 64);
            if (lr == 0)
                part[(size_t)cb * 2048 + orow0 + m * 16 + j] = p;
        }
    }
}

// ---------------------------------------------------------------------------
// prep_a: blocks 0..95 = Wd/Wc transposes (float4 reads, ushort4 writes);
//         rest = vectorized casts, pads, Gram G.
// ---------------------------------------------------------------------------
#define N_DX4 262144
#define N_CX4 131072
#define PREP_A_ELEMS (N_DX4 + N_CX4 + 1024 + 1024 + 1017)

__global__ __launch_bounds__(256) void prep_a(
    const float* __restrict__ dx, const float* __restrict__ cx,
    const float* __restrict__ v,  const float* __restrict__ b1,
    const float* __restrict__ W2,
    const float* __restrict__ Wd, const float* __restrict__ Wc,
    unsigned short* __restrict__ dxb, unsigned short* __restrict__ cxb,
    float* __restrict__ b1p, float* __restrict__ W2p, float* __restrict__ G,
    unsigned short* __restrict__ WdT, unsigned short* __restrict__ WcT)
{
    __shared__ float tile[64][65];
    if (blockIdx.x < 96) {
        int bid = blockIdx.x;
        const float* in; unsigned short* out;
        int ldin, Kout, kt, nt;
        if (bid < 64) { in = Wd; out = WdT; ldin = 512; Kout = 512; kt = bid & 7; nt = bid >> 3; }
        else { bid -= 64; in = Wc; out = WcT; ldin = 512; Kout = 256; kt = bid & 3; nt = bid >> 2; }
        const int k0 = kt * 64, n0 = nt * 64;
        const int tt = threadIdx.x;
        // read: float4 per thread (4 consecutive n), all in-bounds
        const int g4 = (tt & 15) * 4, kr = tt >> 4;
        #pragma unroll
        for (int i = 0; i < 4; ++i) {
            const int kl = kr + i * 16;
            const float4 vv = *reinterpret_cast<const float4*>(&in[(size_t)(k0 + kl) * ldin + n0 + g4]);
            tile[kl][g4+0] = vv.x; tile[kl][g4+1] = vv.y;
            tile[kl][g4+2] = vv.z; tile[kl][g4+3] = vv.w;
        }
        __syncthreads();
        // write: ushort4 per thread (4 consecutive k)
        const int kw4 = (tt & 15) * 4, nr = tt >> 4;
        #pragma unroll
        for (int i = 0; i < 4; ++i) {
            const int nrow = nr + i * 16;
            ushort4 o;
            o.x = f2bf(tile[kw4+0][nrow]); o.y = f2bf(tile[kw4+1][nrow]);
            o.z = f2bf(tile[kw4+2][nrow]); o.w = f2bf(tile[kw4+3][nrow]);
            *reinterpret_cast<ushort4*>(&out[(size_t)(n0 + nrow) * Kout + k0 + kw4]) = o;
        }
        return;
    }
    int j = (blockIdx.x - 96) * 256 + threadIdx.x;
    if (j < N_DX4) {
        const float4 vv = reinterpret_cast<const float4*>(dx)[j];
        ushort4 o;
        o.x = f2bf(vv.x); o.y = f2bf(vv.y); o.z = f2bf(vv.z); o.w = f2bf(vv.w);
        reinterpret_cast<ushort4*>(dxb)[j] = o;
        return;
    }
    j -= N_DX4;
    if (j < N_CX4) {
        const float4 vv = reinterpret_cast<const float4*>(cx)[j];
        ushort4 o;
        o.x = f2bf(vv.x); o.y = f2bf(vv.y); o.z = f2bf(vv.z); o.w = f2bf(vv.w);
        reinterpret_cast<ushort4*>(cxb)[j] = o;
        return;
    }
    j -= N_CX4;
    if (j < 1024) { b1p[j] = (j < 1020) ? b1[j] : 0.f; return; }
    j -= 1024;
    if (j < 1024) { W2p[j] = (j < 1020) ? W2[j] : 0.f; return; }
    j -= 1024;
    if (j >= 1017) return;
    // Gram matrix for channel j: G[j][p] = sum_e v[j][f][e]*v[j][g][e], f<g
    const float* vp = v + (size_t)j * 128;
    float gacc[28];
    #pragma unroll
    for (int p = 0; p < 28; ++p) gacc[p] = 0.f;
    for (int e = 0; e < 16; ++e) {
        float vf[8];
        #pragma unroll
        for (int f = 0; f < 8; ++f) vf[f] = vp[f * 16 + e];
        int p = 0;
        #pragma unroll
        for (int f = 0; f < 8; ++f)
            #pragma unroll
            for (int g = f + 1; g < 8; ++g) { gacc[p] = fmaf(vf[f], vf[g], gacc[p]); ++p; }
    }
    #pragma unroll
    for (int p = 0; p < 28; ++p) G[(size_t)j * 32 + p] = gacc[p];
    #pragma unroll
    for (int p = 28; p < 32; ++p) G[(size_t)j * 32 + p] = 0.f;
}

// ---------------------------------------------------------------------------
// fm_w1t: blocks 0..511 = FM (Gram form); 512..1023 = W1 transpose
// (float4 reads w/ edge masking, ushort4 writes).
// ---------------------------------------------------------------------------
__global__ __launch_bounds__(256) void fm_w1t(
    const float* __restrict__ G,
    const float* __restrict__ lin_w, const float* __restrict__ lin_b,
    unsigned short* __restrict__ resb,
    const float* __restrict__ W1, unsigned short* __restrict__ W1T)
{
    if (blockIdx.x >= 512) {
        __shared__ float tile[64][65];
        const int bid = blockIdx.x - 512;
        const int kt = bid & 31, nt = bid >> 5;  // 32 k-tiles x 16 n-tiles
        const int k0 = kt * 64, n0 = nt * 64;
        const int tt = threadIdx.x;
        const int g4 = (tt & 15) * 4, kr = tt >> 4;
        #pragma unroll
        for (int i = 0; i < 4; ++i) {
            const int kl = kr + i * 16;
            const int gk = k0 + kl;
            float4 vv = make_float4(0.f, 0.f, 0.f, 0.f);
            if (gk < 2041) {
                if (n0 + g4 + 3 < 1020) {
                    vv = *reinterpret_cast<const float4*>(&W1[(size_t)gk * 1020 + n0 + g4]);
                } else {
                    const int gn = n0 + g4;
                    vv.x = (gn + 0 < 1020) ? W1[(size_t)gk * 1020 + gn + 0] : 0.f;
                    vv.y = (gn + 1 < 1020) ? W1[(size_t)gk * 1020 + gn + 1] : 0.f;
                    vv.z = (gn + 2 < 1020) ? W1[(size_t)gk * 1020 + gn + 2] : 0.f;
                    vv.w = (gn + 3 < 1020) ? W1[(size_t)gk * 1020 + gn + 3] : 0.f;
                }
            }
            tile[kl][g4+0] = vv.x; tile[kl][g4+1] = vv.y;
            tile[kl][g4+2] = vv.z; tile[kl][g4+3] = vv.w;
        }
        __syncthreads();
        const int kw4 = (tt & 15) * 4, nr = tt >> 4;
        #pragma unroll
        for (int i = 0; i < 4; ++i) {
            const int nrow = nr + i * 16;
            ushort4 o;
            o.x = f2bf(tile[kw4+0][nrow]); o.y = f2bf(tile[kw4+1][nrow]);
            o.z = f2bf(tile[kw4+2][nrow]); o.w = f2bf(tile[kw4+3][nrow]);
            *reinterpret_cast<ushort4*>(&W1T[(size_t)(n0 + nrow) * 2048 + k0 + kw4]) = o;
        }
        return;
    }

    __shared__ float xs[4][1032];
    const int r0 = blockIdx.x * 4;
    const int t  = threadIdx.x;

    #pragma unroll
    for (int r = 0; r < 4; ++r) {
        const ushort4 u = reinterpret_cast<const ushort4*>(resb + (size_t)(r0 + r) * 2048)[t];
        xs[r][t*4+0] = bf2f(u.x); xs[r][t*4+1] = bf2f(u.y);
        xs[r][t*4+2] = bf2f(u.z); xs[r][t*4+3] = bf2f(u.w);
    }
    if (t < 8) {
        #pragma unroll
        for (int r = 0; r < 4; ++r) xs[r][1024 + t] = 0.f;
    }
    __syncthreads();

    float lw[8];
    #pragma unroll
    for (int f = 0; f < 8; ++f) lw[f] = lin_w[f];
    const float lb = lin_b[0];

    const int ch0 = t * 4;
    float xw[4][12];
    #pragma unroll
    for (int r = 0; r < 4; ++r) {
        const float4 a = *reinterpret_cast<const float4*>(&xs[r][ch0]);
        const float4 b = *reinterpret_cast<const float4*>(&xs[r][ch0 + 4]);
        const float4 c = *reinterpret_cast<const float4*>(&xs[r][ch0 + 8]);
        xw[r][0]=a.x; xw[r][1]=a.y; xw[r][2]=a.z; xw[r][3]=a.w;
        xw[r][4]=b.x; xw[r][5]=b.y; xw[r][6]=b.z; xw[r][7]=b.w;
        xw[r][8]=c.x; xw[r][9]=c.y; xw[r][10]=c.z; xw[r][11]=c.w;
    }

    #pragma unroll
    for (int c = 0; c < 4; ++c) {
        const int ch = ch0 + c;
        float outv[4] = {0.f, 0.f, 0.f, 0.f};
        if (ch < 1017) {
            f32x4 Gv[7];
            const float* gp = G + (size_t)ch * 32;
            #pragma unroll
            for (int i = 0; i < 7; ++i) Gv[i] = *reinterpret_cast<const f32x4*>(gp + i * 4);
            float lin[4], fmv[4] = {0.f, 0.f, 0.f, 0.f};
            #pragma unroll
            for (int r = 0; r < 4; ++r) {
                float s = lb;
                #pragma unroll
                for (int f = 0; f < 8; ++f) s = fmaf(xw[r][c+f], lw[f], s);
                lin[r] = s;
            }
            int p = 0;
            #pragma unroll
            for (int f = 0; f < 8; ++f) {
                #pragma unroll
                for (int g = f + 1; g < 8; ++g) {
                    const float gfg = Gv[p >> 2][p & 3];
                    #pragma unroll
                    for (int r = 0; r < 4; ++r)
                        fmv[r] = fmaf(xw[r][c+f] * xw[r][c+g], gfg, fmv[r]);
                    ++p;
                }
            }
            #pragma unroll
            for (int r = 0; r < 4; ++r) outv[r] = lin[r] + fmv[r];
        }
        #pragma unroll
        for (int r = 0; r < 4; ++r)
            resb[(size_t)(r0 + r) * 2048 + 1024 + ch] = f2bf(outv[r]);
    }
}

// Final: out[b] = sigmoid(sum_{i<16} part[i][b] + b2)
__global__ __launch_bounds__(64) void final2_kernel(
    const float* __restrict__ part, const float* __restrict__ b2,
    float* __restrict__ out)
{
    const int b = blockIdx.x * 64 + threadIdx.x;
    float s = b2[0];
    #pragma unroll
    for (int i = 0; i < 16; ++i) s += part[(size_t)i * 2048 + b];
    out[b] = 1.f / (1.f + expf(-s));
}

extern "C" void kernel_launch(void* const* d_in, const int* in_sizes, int n_in,
                              void* d_out, int out_size, void* d_ws, size_t ws_size,
                              hipStream_t stream)
{
    const float* dx = (const float*)d_in[0];
    const float* cx = (const float*)d_in[1];
    const float* Wd = (const float*)d_in[2];
    const float* bd = (const float*)d_in[3];
    const float* Wc = (const float*)d_in[4];
    const float* bc = (const float*)d_in[5];
    const float* v  = (const float*)d_in[6];
    const float* lw = (const float*)d_in[7];
    const float* lb = (const float*)d_in[8];
    const float* W1 = (const float*)d_in[9];
    const float* b1 = (const float*)d_in[10];
    const float* W2 = (const float*)d_in[11];
    const float* b2 = (const float*)d_in[12];
    float* out = (float*)d_out;

    char* ws = (char*)d_ws;
    unsigned short* resb = (unsigned short*)(ws);                              // 8 MB
    float*          part = (float*)(ws + (8u << 20));                          // 128 KB
    unsigned short* dxb  = (unsigned short*)(ws + (9u << 20));                 // 2 MB
    unsigned short* cxb  = (unsigned short*)(ws + (11u << 20));                // 1 MB
    unsigned short* WdT  = (unsigned short*)(ws + (12u << 20));                // 512 KB
    unsigned short* WcT  = (unsigned short*)(ws + (12u << 20) + (512u << 10)); // 256 KB
    unsigned short* W1T  = (unsigned short*)(ws + (13u << 20));                // 4 MB
    float*          G    = (float*)(ws + (17u << 20));                         // 132 KB
    float*          b1p  = (float*)(ws + (17u << 20) + (192u << 10));          // 4 KB
    float*          W2p  = (float*)(ws + (17u << 20) + (196u << 10));          // 4 KB

    const int prep_a_blocks = 96 + (PREP_A_ELEMS + 255) / 256;
    hipLaunchKernelGGL(prep_a, dim3(prep_a_blocks), dim3(256), 0, stream,
                       dx, cx, v, b1, W2, Wd, Wc,
                       dxb, cxb, b1p, W2p, G, WdT, WcT);
    hipLaunchKernelGGL(gemm_top_mfma, dim3(256), dim3(512), 0, stream,
                       dxb, cxb, WdT, WcT, bd, bc, resb);
    hipLaunchKernelGGL(fm_w1t, dim3(1024), dim3(256), 0, stream,
                       G, lw, lb, resb, W1, W1T);
    hipLaunchKernelGGL(gemm_w1_mfma, dim3(256), dim3(512), 0, stream,
                       resb, W1T, b1p, W2p, part);
    hipLaunchKernelGGL(final2_kernel, dim3(32), dim3(64), 0, stream,
                       part, b2, out);
}